// Round 1
// 6518.968 us; speedup vs baseline: 1.1965x; 1.1965x over previous
//
#include <hip/hip_runtime.h>

typedef __bf16 bf16;
typedef short s8v  __attribute__((ext_vector_type(8)));
typedef short s4v  __attribute__((ext_vector_type(4)));
typedef float f4v  __attribute__((ext_vector_type(4)));
typedef bf16  bf8v __attribute__((ext_vector_type(8)));
typedef bf16  bf4v __attribute__((ext_vector_type(4)));

#define NTOK 3160      // 24 joints + 16*196 frame tokens
#define MROWS 6320     // 2*NTOK
#define MPAD  6400

__device__ __forceinline__ float bf2f(short v) {
    return __uint_as_float(((unsigned)(unsigned short)v) << 16);
}
__device__ __forceinline__ void split2(float v, bf16* hi, bf16* lo) {
    bf16 h = (bf16)v;
    *hi = h;
    *lo = (bf16)(v - (float)h);
}

// ---------------------------------------------------------------- transpose W (f32 KxN -> bf16 hi/lo NxK)
__global__ void transpose_w(const float* __restrict__ W, bf16* __restrict__ Wth,
                            bf16* __restrict__ Wtl, int K_, int N_) {
    __shared__ float tile[32][33];
    int l = blockIdx.z;
    const float* Ws = W + (long)l * K_ * N_;
    long obase = (long)l * K_ * N_;
    int n0 = blockIdx.x * 32, k0 = blockIdx.y * 32;
    int tx = threadIdx.x & 31, ty = threadIdx.x >> 5;   // 32 x 8
    #pragma unroll
    for (int i = 0; i < 32; i += 8)
        tile[ty + i][tx] = Ws[(long)(k0 + ty + i) * N_ + n0 + tx];
    __syncthreads();
    #pragma unroll
    for (int i = 0; i < 32; i += 8) {
        long oidx = obase + (long)(n0 + ty + i) * K_ + k0 + tx;
        split2(tile[tx][ty + i], Wth + oidx, Wtl + oidx);
    }
}

// ---------------------------------------------------------------- patchify: video -> patches hi/lo [6400][512]
__global__ void patchify(const float* __restrict__ video, bf16* __restrict__ ph,
                         bf16* __restrict__ pl) {
    int idx = blockIdx.x * 256 + threadIdx.x;          // over 6400*512
    int row = idx >> 9, fc = idx & 511;
    if (row >= 6272) { ph[idx] = (bf16)0.f; pl[idx] = (bf16)0.f; return; }
    int bi = row / 3136, t = row % 3136;
    int fi = t / 196, pp = t % 196, hp_i = pp / 14, wp_i = pp % 14;
    int phh = fc >> 5, pw = (fc >> 1) & 15, c = fc & 1;
    long vidx = ((((long)(bi * 16 + fi) * 2 + c) * 224) + hp_i * 16 + phh) * 224 + wp_i * 16 + pw;
    split2(video[vidx], ph + idx, pl + idx);
}

// ---------------------------------------------------------------- x joint-token init
__global__ void xinit(const float* __restrict__ jt, float* __restrict__ x) {
    int idx = blockIdx.x * 256 + threadIdx.x;          // over 2*24*512
    int b = idx / (24 * 512), r = idx % (24 * 512);
    x[(long)b * NTOK * 512 + r] = jt[r];
}

// ---------------------------------------------------------------- axial rotary tables [196][32]
__global__ void sincos_k(float* __restrict__ sinb, float* __restrict__ cosb) {
    int idx = blockIdx.x * 256 + threadIdx.x;
    if (idx >= 196 * 32) return;
    int p = idx >> 5, i = idx & 31;
    int hp_i = p / 14, wp_i = p % 14;
    float coord = (i < 16) ? (-1.f + 2.f * hp_i / 13.f) : (-1.f + 2.f * wp_i / 13.f);
    int si = i & 15;
    float scale = exp2f(si * (float)(2.3219280948873623 / 15.0)); // 2^linspace(0,log2(5),16)
    float ang = coord * scale * 3.14159265358979323846f;
    sinb[idx] = sinf(ang);
    cosb[idx] = cosf(ang);
}

// ---------------------------------------------------------------- LayerNorm fp32 -> bf16 hi/lo (wave per row)
__global__ void ln_kernel(const float* __restrict__ x, const float* __restrict__ w,
                          const float* __restrict__ bb, bf16* __restrict__ oh,
                          bf16* __restrict__ ol, int nreal, int jmap) {
    int row = blockIdx.x * 4 + (threadIdx.x >> 6);
    int lane = threadIdx.x & 63;
    if (row >= nreal) {
        bf8v z;
        #pragma unroll
        for (int i = 0; i < 8; ++i) z[i] = (bf16)0.f;
        *(bf8v*)(oh + (long)row * 512 + lane * 8) = z;
        *(bf8v*)(ol + (long)row * 512 + lane * 8) = z;
        return;
    }
    long src = jmap ? ((long)(row / 24) * NTOK + row % 24) : row;
    const float* xr = x + src * 512 + lane * 8;
    f4v a = *(const f4v*)xr;
    f4v b4 = *(const f4v*)(xr + 4);
    float s = 0.f, sq = 0.f;
    #pragma unroll
    for (int i = 0; i < 4; ++i) { s += a[i] + b4[i]; sq += a[i]*a[i] + b4[i]*b4[i]; }
    #pragma unroll
    for (int off = 32; off; off >>= 1) { s += __shfl_xor(s, off); sq += __shfl_xor(sq, off); }
    float mean = s * (1.f / 512.f);
    float var = sq * (1.f / 512.f) - mean * mean;
    float r = rsqrtf(var + 1e-5f);
    f4v wv0 = *(const f4v*)(w + lane * 8),  wv1 = *(const f4v*)(w + lane * 8 + 4);
    f4v bv0 = *(const f4v*)(bb + lane * 8), bv1 = *(const f4v*)(bb + lane * 8 + 4);
    bf8v vh, vl;
    #pragma unroll
    for (int i = 0; i < 4; ++i) {
        float v0 = (a[i]  - mean) * r * wv0[i] + bv0[i];
        float v1 = (b4[i] - mean) * r * wv1[i] + bv1[i];
        bf16 h0 = (bf16)v0, h1_ = (bf16)v1;
        vh[i] = h0;     vl[i] = (bf16)(v0 - (float)h0);
        vh[i + 4] = h1_; vl[i + 4] = (bf16)(v1 - (float)h1_);
    }
    *(bf8v*)(oh + (long)row * 512 + lane * 8) = vh;
    *(bf8v*)(ol + (long)row * 512 + lane * 8) = vl;
}

// ---------------------------------------------------------------- gated GELU (exact): h1 f32 [6400][4096] -> hg hi/lo [6400][2048]
__global__ void gate_kernel(const float* __restrict__ h1, bf16* __restrict__ hgh,
                            bf16* __restrict__ hgl) {
    int idx = blockIdx.x * 256 + threadIdx.x;          // over 6400*512 groups of 4
    int r = idx >> 9, c4 = (idx & 511) * 4;
    long abase = (long)r * 4096 + c4;
    f4v av = *(const f4v*)(h1 + abase);
    f4v gv = *(const f4v*)(h1 + abase + 2048);
    bf4v oh, ol;
    #pragma unroll
    for (int i = 0; i < 4; ++i) {
        float a = av[i], g = gv[i];
        float gl = 0.5f * g * (1.f + erff(g * 0.70710678118654752f));
        float v = a * gl;
        bf16 h = (bf16)v;
        oh[i] = h; ol[i] = (bf16)(v - (float)h);
    }
    long obase = (long)r * 2048 + c4;
    *(bf4v*)(hgh + obase) = oh;
    *(bf4v*)(hgl + obase) = ol;
}

// ---------------------------------------------------------------- split-bf16 MFMA GEMM: C = A*B with A=Ah+Al, B=Bh+Bl
// 3-term: Ah*Bh + Ah*Bl + Al*Bh; fp32 accumulate -> ~fp32-accurate.
// EPI: 0 = f32 out (+bias), 2 = residual add into f32 x[.][512], 3 = patch row-remap into x
template<int EPI>
__global__ __launch_bounds__(256)
void gemm3_bt(const bf16* __restrict__ Ah, const bf16* __restrict__ Al,
              const bf16* __restrict__ Bh, const bf16* __restrict__ Bl,
              const float* __restrict__ bias, float* __restrict__ outF,
              int M, int N, int K, int Mstore) {
    __shared__ bf16 LAh[128 * 32];
    __shared__ bf16 LAl[128 * 32];
    __shared__ bf16 LBh[128 * 32];
    __shared__ bf16 LBl[128 * 32];
    int tid = threadIdx.x;
    int wave = tid >> 6, lane = tid & 63;
    long m0 = (long)blockIdx.y * 128;
    long n0 = (long)blockIdx.x * 128;
    int wm = (wave >> 1) * 64, wn = (wave & 1) * 64;
    f4v acc[4][4] = {};
    int r16 = lane & 15, q4 = lane >> 4;
    int srow = lane >> 2;          // row within 16-row slab (identity mapping)
    int cg = lane & 3;             // chunk within 32-col row (identity mapping)

    const bf16* Agh = Ah + m0 * K;
    const bf16* Agl = Al + m0 * K;
    const bf16* Bgh = Bh + n0 * K;
    const bf16* Bgl = Bl + n0 * K;

    for (int kb = 0; kb < K; kb += 32) {
        #pragma unroll
        for (int ss = 0; ss < 2; ++ss) {
            int s = wave * 2 + ss;
            long roff = (long)(s * 16 + srow) * K + kb + cg * 8;
            int ldso = s * 512;   // elements
            __builtin_amdgcn_global_load_lds(
                (const __attribute__((address_space(1))) void*)(Agh + roff),
                (__attribute__((address_space(3))) void*)(LAh + ldso), 16, 0, 0);
            __builtin_amdgcn_global_load_lds(
                (const __attribute__((address_space(1))) void*)(Agl + roff),
                (__attribute__((address_space(3))) void*)(LAl + ldso), 16, 0, 0);
            __builtin_amdgcn_global_load_lds(
                (const __attribute__((address_space(1))) void*)(Bgh + roff),
                (__attribute__((address_space(3))) void*)(LBh + ldso), 16, 0, 0);
            __builtin_amdgcn_global_load_lds(
                (const __attribute__((address_space(1))) void*)(Bgl + roff),
                (__attribute__((address_space(3))) void*)(LBl + ldso), 16, 0, 0);
        }
        __syncthreads();
        s8v ah[4], al[4], bh[4], bl[4];
        #pragma unroll
        for (int mb = 0; mb < 4; ++mb) {
            int off = (wm + mb * 16 + r16) * 32 + q4 * 8;
            ah[mb] = *(const s8v*)(LAh + off);
            al[mb] = *(const s8v*)(LAl + off);
        }
        #pragma unroll
        for (int nb = 0; nb < 4; ++nb) {
            int off = (wn + nb * 16 + r16) * 32 + q4 * 8;
            bh[nb] = *(const s8v*)(LBh + off);
            bl[nb] = *(const s8v*)(LBl + off);
        }
        #pragma unroll
        for (int mb = 0; mb < 4; ++mb)
            #pragma unroll
            for (int nb = 0; nb < 4; ++nb) {
                acc[mb][nb] = __builtin_amdgcn_mfma_f32_16x16x32_bf16(ah[mb], bh[nb], acc[mb][nb], 0, 0, 0);
                acc[mb][nb] = __builtin_amdgcn_mfma_f32_16x16x32_bf16(ah[mb], bl[nb], acc[mb][nb], 0, 0, 0);
                acc[mb][nb] = __builtin_amdgcn_mfma_f32_16x16x32_bf16(al[mb], bh[nb], acc[mb][nb], 0, 0, 0);
            }
        __syncthreads();
    }
    #pragma unroll
    for (int nb = 0; nb < 4; ++nb) {
        int col = (int)n0 + wn + nb * 16 + r16;
        float bv = bias ? bias[col] : 0.f;
        #pragma unroll
        for (int mb = 0; mb < 4; ++mb) {
            #pragma unroll
            for (int i = 0; i < 4; ++i) {
                long row = m0 + wm + mb * 16 + q4 * 4 + i;
                if (row >= Mstore) continue;
                float v = acc[mb][nb][i] + bv;
                if (EPI == 0) outF[row * N + col] = v;
                else if (EPI == 2) outF[row * 512 + col] += v;
                else {  // EPI == 3: rows are b*3136+t -> x row b*3160 + 24 + t
                    long orow = row + 24 * (row / 3136 + 1);
                    outF[orow * 512 + col] = v;
                }
            }
        }
    }
    (void)M;
}

// ---------------------------------------------------------------- joints attention: S = (jq*scale) @ k^T over all 3160 keys
__global__ void jattn_scores(const float* __restrict__ qkv, float* __restrict__ S) {
    int kt = blockIdx.x, bh = blockIdx.y;
    int b = bh >> 3, h = bh & 7;
    long rowbase = (long)b * NTOK;
    __shared__ float qs[24][64];
    __shared__ float ks[64][65];
    int tid = threadIdx.x;
    for (int idx = tid; idx < 24 * 64; idx += 256) {
        int j = idx >> 6, d = idx & 63;
        qs[j][d] = qkv[(rowbase + j) * 1536 + h * 64 + d] * 0.125f;
    }
    for (int idx = tid; idx < 64 * 64; idx += 256) {
        int j = idx >> 6, d = idx & 63;
        int tok = kt * 64 + j;
        ks[j][d] = (tok < NTOK) ? qkv[(rowbase + tok) * 1536 + 512 + h * 64 + d] : 0.f;
    }
    __syncthreads();
    for (int idx = tid; idx < 24 * 64; idx += 256) {
        int qi = idx >> 6, kk = idx & 63;
        int tok = kt * 64 + kk;
        if (tok >= NTOK) continue;
        float acc = 0.f;
        #pragma unroll 8
        for (int d = 0; d < 64; ++d) acc += qs[qi][d] * ks[kk][d];
        S[((long)bh * 24 + qi) * NTOK + tok] = acc;
    }
}

__global__ void jattn_softmax(float* __restrict__ S) {
    int r = blockIdx.x;                      // 0..383
    float* row = S + (long)r * NTOK;
    int tid = threadIdx.x, wave = tid >> 6, lane = tid & 63;
    __shared__ float wred[4];
    float m = -3e38f;
    for (int i = tid; i < NTOK; i += 256) m = fmaxf(m, row[i]);
    #pragma unroll
    for (int off = 32; off; off >>= 1) m = fmaxf(m, __shfl_xor(m, off));
    if (lane == 0) wred[wave] = m;
    __syncthreads();
    m = fmaxf(fmaxf(wred[0], wred[1]), fmaxf(wred[2], wred[3]));
    __syncthreads();
    float s = 0.f;
    for (int i = tid; i < NTOK; i += 256) { float e = __expf(row[i] - m); row[i] = e; s += e; }
    #pragma unroll
    for (int off = 32; off; off >>= 1) s += __shfl_xor(s, off);
    if (lane == 0) wred[wave] = s;
    __syncthreads();
    s = wred[0] + wred[1] + wred[2] + wred[3];
    float inv = 1.f / s;
    for (int i = tid; i < NTOK; i += 256) row[i] *= inv;
}

__global__ void jattn_out(const float* __restrict__ qkv, const float* __restrict__ S,
                          bf16* __restrict__ aoh, bf16* __restrict__ aol) {
    int q = blockIdx.x, bh = blockIdx.y;
    int b = bh >> 3, h = bh & 7;
    int tid = threadIdx.x, wave = tid >> 6, lane = tid & 63;
    const float* P = S + ((long)bh * 24 + q) * NTOK;
    long rowbase = (long)b * NTOK;
    float o = 0.f;
    int j0 = wave * 790, j1 = j0 + 790;      // 3160 = 4*790
    for (int j = j0; j < j1; ++j)
        o += P[j] * qkv[(rowbase + j) * 1536 + 1024 + h * 64 + lane];
    __shared__ float ob[4][64];
    ob[wave][lane] = o;
    __syncthreads();
    if (wave == 0) {
        float v = ob[0][lane] + ob[1][lane] + ob[2][lane] + ob[3][lane];
        long oidx = (rowbase + q) * 512 + h * 64 + lane;
        split2(v, aoh + oidx, aol + oidx);
    }
}

// ---------------------------------------------------------------- frame attention, MFMA version
// One block per (frame, b*head). 196 queries (pad 224), 220 keys (24 joints + 196 rotary frame keys, pad 224).
// Precision: K single bf16 (as before), Q split hi/lo (4-term QK^T MFMA == f32 Q),
// softmax f32 in D-fragment registers, PV 3-term split (Ph*Vh + Pl*Vh + Ph*Vl ~= f32).
// LDS layouts (all XOR-swizzled; swizzle confined to in-row bits => bijective):
//   Ks/Qh/Ql: [row 224][d 64] bf16, 128B rows, byte ^= (row&7)<<4
//   Vh/Vl   : [d 64][key 224] bf16 (transposed), 448B rows, byte ^= (row&3)<<4
//   Ph/Pl   : per-wave [16][64-pad] bf16 scratch (only cols 0..31 used), byte ^= (row&7)<<4
// MFMA conventions identical to gemm3_bt: A read [m][k] (row=lane&15, k=(lane>>4)*8+j),
// B read [n][k], D row=(lane>>4)*4+i, col=lane&15.
__global__ __launch_bounds__(256, 1)
void frame_attn(const float* __restrict__ qkv, const float* __restrict__ sinb,
                const float* __restrict__ cosb, bf16* __restrict__ aoh,
                bf16* __restrict__ aol) {
    int fr = blockIdx.x, bh = blockIdx.y;
    int b = bh >> 3, h = bh & 7;
    long rowbase = (long)b * NTOK;
    int t0 = 24 + fr * 196;

    __shared__ __align__(16) bf16 Ks[224 * 64];     // 28672 B
    __shared__ __align__(16) bf16 Qh[224 * 64];     // 28672
    __shared__ __align__(16) bf16 Ql[224 * 64];     // 28672
    __shared__ __align__(16) bf16 Vh[64 * 224];     // 28672
    __shared__ __align__(16) bf16 Vl[64 * 224];     // 28672
    __shared__ __align__(16) bf16 Ph[4 * 16 * 64];  // 8192
    __shared__ __align__(16) bf16 Pl[4 * 16 * 64];  // 8192  => total 159744 B

    int tid = threadIdx.x;
    // ---- stage K (rotary frame keys), Q (rotary+scale, hi/lo), V (hi/lo, transposed)
    for (int idx = tid; idx < 224 * 16; idx += 256) {
        int j = idx >> 4, d4 = idx & 15;
        int tok = (j < 24) ? j : (t0 + j - 24);
        // K
        bf4v kb;
        if (j < 220) {
            f4v kv = *(const f4v*)(qkv + (rowbase + tok) * 1536 + 512 + h * 64 + d4 * 4);
            if (j >= 24) {
                int pos = j - 24;
                float sn0 = sinb[pos * 32 + d4 * 2],     cs0 = cosb[pos * 32 + d4 * 2];
                float sn1 = sinb[pos * 32 + d4 * 2 + 1], cs1 = cosb[pos * 32 + d4 * 2 + 1];
                kb[0] = (bf16)(kv[0] * cs0 - kv[1] * sn0);
                kb[1] = (bf16)(kv[1] * cs0 + kv[0] * sn0);
                kb[2] = (bf16)(kv[2] * cs1 - kv[3] * sn1);
                kb[3] = (bf16)(kv[3] * cs1 + kv[2] * sn1);
            } else {
                kb[0] = (bf16)kv[0]; kb[1] = (bf16)kv[1];
                kb[2] = (bf16)kv[2]; kb[3] = (bf16)kv[3];
            }
        } else {
            kb[0] = kb[1] = kb[2] = kb[3] = (bf16)0.f;
        }
        *(bf4v*)((char*)Ks + ((j * 128 + d4 * 8) ^ ((j & 7) << 4))) = kb;
        // Q (queries are only the 196 frame tokens)
        bf4v qhv, qlv;
        if (j < 196) {
            f4v qv = *(const f4v*)(qkv + (rowbase + t0 + j) * 1536 + h * 64 + d4 * 4);
            float sn0 = sinb[j * 32 + d4 * 2],     cs0 = cosb[j * 32 + d4 * 2];
            float sn1 = sinb[j * 32 + d4 * 2 + 1], cs1 = cosb[j * 32 + d4 * 2 + 1];
            float r0 = (qv[0] * cs0 - qv[1] * sn0) * 0.125f;
            float r1 = (qv[1] * cs0 + qv[0] * sn0) * 0.125f;
            float r2 = (qv[2] * cs1 - qv[3] * sn1) * 0.125f;
            float r3 = (qv[3] * cs1 + qv[2] * sn1) * 0.125f;
            bf16 h0 = (bf16)r0; qhv[0] = h0; qlv[0] = (bf16)(r0 - (float)h0);
            bf16 h1 = (bf16)r1; qhv[1] = h1; qlv[1] = (bf16)(r1 - (float)h1);
            bf16 h2 = (bf16)r2; qhv[2] = h2; qlv[2] = (bf16)(r2 - (float)h2);
            bf16 h3 = (bf16)r3; qhv[3] = h3; qlv[3] = (bf16)(r3 - (float)h3);
        } else {
            qhv[0] = qhv[1] = qhv[2] = qhv[3] = (bf16)0.f;
            qlv[0] = qlv[1] = qlv[2] = qlv[3] = (bf16)0.f;
        }
        int qoff = (j * 128 + d4 * 8) ^ ((j & 7) << 4);
        *(bf4v*)((char*)Qh + qoff) = qhv;
        *(bf4v*)((char*)Ql + qoff) = qlv;
        // V -> transposed [d][key]
        f4v vv = {0.f, 0.f, 0.f, 0.f};
        if (j < 220)
            vv = *(const f4v*)(qkv + (rowbase + tok) * 1536 + 1024 + h * 64 + d4 * 4);
        #pragma unroll
        for (int k = 0; k < 4; ++k) {
            int d = d4 * 4 + k;
            int vo = (d * 448 + j * 2) ^ ((d & 3) << 4);
            bf16 hv = (bf16)vv[k];
            *(bf16*)((char*)Vh + vo) = hv;
            *(bf16*)((char*)Vl + vo) = (bf16)(vv[k] - (float)hv);
        }
    }
    __syncthreads();

    int w = tid >> 6, lane = tid & 63;
    int r16 = lane & 15, q4 = lane >> 4;
    char* PhB = (char*)Ph + w * 2048;   // per-wave scratch, no barrier needed
    char* PlB = (char*)Pl + w * 2048;
    int nt = (w == 3) ? 2 : 4;          // q-tiles 0..13 over 4 waves

    for (int jt = 0; jt < nt; ++jt) {
        int qt = w * 4 + jt;
        int qrow = qt * 16 + r16;
        int qsw = (qrow & 7) << 4;
        s8v ah0 = *(const s8v*)((char*)Qh + ((qrow * 128 + q4 * 16) ^ qsw));
        s8v ah1 = *(const s8v*)((char*)Qh + ((qrow * 128 + 64 + q4 * 16) ^ qsw));
        s8v al0 = *(const s8v*)((char*)Ql + ((qrow * 128 + q4 * 16) ^ qsw));
        s8v al1 = *(const s8v*)((char*)Ql + ((qrow * 128 + 64 + q4 * 16) ^ qsw));
        f4v s[14];
        #pragma unroll
        for (int kt = 0; kt < 14; ++kt) {
            int krow = kt * 16 + r16;
            int ksw = (krow & 7) << 4;
            s8v b0 = *(const s8v*)((char*)Ks + ((krow * 128 + q4 * 16) ^ ksw));
            s8v b1 = *(const s8v*)((char*)Ks + ((krow * 128 + 64 + q4 * 16) ^ ksw));
            f4v a = {0.f, 0.f, 0.f, 0.f};
            a = __builtin_amdgcn_mfma_f32_16x16x32_bf16(ah0, b0, a, 0, 0, 0);
            a = __builtin_amdgcn_mfma_f32_16x16x32_bf16(ah1, b1, a, 0, 0, 0);
            a = __builtin_amdgcn_mfma_f32_16x16x32_bf16(al0, b0, a, 0, 0, 0);
            a = __builtin_amdgcn_mfma_f32_16x16x32_bf16(al1, b1, a, 0, 0, 0);
            s[kt] = a;
        }
        // mask pad keys 220..223 (tile 13, cols 12..15)
        if (r16 >= 12) { s[13][0] = -3e38f; s[13][1] = -3e38f; s[13][2] = -3e38f; s[13][3] = -3e38f; }
        // softmax over keys: row = q4*4+i, spread over the 16 lanes of the r16 group
        f4v m = s[0];
        #pragma unroll
        for (int kt = 1; kt < 14; ++kt)
            #pragma unroll
            for (int i = 0; i < 4; ++i) m[i] = fmaxf(m[i], s[kt][i]);
        #pragma unroll
        for (int off = 1; off <= 8; off <<= 1)
            #pragma unroll
            for (int i = 0; i < 4; ++i) m[i] = fmaxf(m[i], __shfl_xor(m[i], off));
        f4v sum = {0.f, 0.f, 0.f, 0.f};
        #pragma unroll
        for (int kt = 0; kt < 14; ++kt)
            #pragma unroll
            for (int i = 0; i < 4; ++i) { s[kt][i] = __expf(s[kt][i] - m[i]); sum[i] += s[kt][i]; }
        #pragma unroll
        for (int off = 1; off <= 8; off <<= 1)
            #pragma unroll
            for (int i = 0; i < 4; ++i) sum[i] += __shfl_xor(sum[i], off);
        f4v inv;
        #pragma unroll
        for (int i = 0; i < 4; ++i) inv[i] = 1.f / sum[i];
        #pragma unroll
        for (int kt = 0; kt < 14; ++kt)
            #pragma unroll
            for (int i = 0; i < 4; ++i) s[kt][i] *= inv[i];

        // PV: per 32-key chunk, transpose P (D-layout -> A-frag layout) via per-wave LDS scratch
        f4v o[4] = {{0.f,0.f,0.f,0.f},{0.f,0.f,0.f,0.f},{0.f,0.f,0.f,0.f},{0.f,0.f,0.f,0.f}};
        #pragma unroll
        for (int ks = 0; ks < 7; ++ks) {
            #pragma unroll
            for (int half = 0; half < 2; ++half) {
                int kt = ks * 2 + half;
                #pragma unroll
                for (int i = 0; i < 4; ++i) {
                    int prow = q4 * 4 + i;
                    int pbyte = (prow * 128 + (half * 16 + r16) * 2) ^ ((prow & 7) << 4);
                    float p = s[kt][i];
                    bf16 hb = (bf16)p;
                    *(bf16*)(PhB + pbyte) = hb;
                    *(bf16*)(PlB + pbyte) = (bf16)(p - (float)hb);
                }
            }
            int abyte = (r16 * 128 + q4 * 16) ^ ((r16 & 7) << 4);
            s8v pah = *(const s8v*)(PhB + abyte);
            s8v pal = *(const s8v*)(PlB + abyte);
            #pragma unroll
            for (int dt = 0; dt < 4; ++dt) {
                int vrow = dt * 16 + r16;
                int vbyte = (vrow * 448 + ks * 64 + q4 * 16) ^ ((vrow & 3) << 4);
                s8v bvh = *(const s8v*)((char*)Vh + vbyte);
                s8v bvl = *(const s8v*)((char*)Vl + vbyte);
                o[dt] = __builtin_amdgcn_mfma_f32_16x16x32_bf16(pah, bvh, o[dt], 0, 0, 0);
                o[dt] = __builtin_amdgcn_mfma_f32_16x16x32_bf16(pal, bvh, o[dt], 0, 0, 0);
                o[dt] = __builtin_amdgcn_mfma_f32_16x16x32_bf16(pah, bvl, o[dt], 0, 0, 0);
            }
        }
        // store: D row=(q4*4+i)=query-in-tile, col=r16=d-in-dt
        #pragma unroll
        for (int dt = 0; dt < 4; ++dt)
            #pragma unroll
            for (int i = 0; i < 4; ++i) {
                int query = qt * 16 + q4 * 4 + i;
                if (query < 196) {
                    long oidx = (rowbase + t0 + query) * 512 + h * 64 + dt * 16 + r16;
                    split2(o[dt][i], aoh + oidx, aol + oidx);
                }
            }
    }
}

// ----------------------------------------------------------------
extern "C" void kernel_launch(void* const* d_in, const int* in_sizes, int n_in,
                              void* d_out, int out_size, void* d_ws, size_t ws_size,
                              hipStream_t stream) {
    const float* video        = (const float*)d_in[0];
    const float* patch_w      = (const float*)d_in[1];
    const float* patch_b      = (const float*)d_in[2];
    const float* joints_token = (const float*)d_in[3];
    const float* ln_attn_w    = (const float*)d_in[4];
    const float* ln_attn_b    = (const float*)d_in[5];
    const float* qkv_w        = (const float*)d_in[6];
    const float* attn_out_w   = (const float*)d_in[7];
    const float* attn_out_b   = (const float*)d_in[8];
    const float* ln_ff_w      = (const float*)d_in[9];
    const float* ln_ff_b      = (const float*)d_in[10];
    const float* ff1_w        = (const float*)d_in[11];
    const float* ff1_b        = (const float*)d_in[12];
    const float* ff2_w        = (const float*)d_in[13];
    const float* ff2_b        = (const float*)d_in[14];
    const float* ln_out_w     = (const float*)d_in[15];
    const float* ln_out_b     = (const float*)d_in[16];
    const float* out_w        = (const float*)d_in[17];
    const float* out_b        = (const float*)d_in[18];
    float* out = (float*)d_out;

    char* ws = (char*)d_ws;
    size_t off = 0;
    auto alloc = [&](size_t bytes) { void* p = ws + off; off += (bytes + 255) & ~(size_t)255; return p; };

    // ---- common buffers
    float* x    = (float*)alloc((long)MPAD * 512 * 4);
    bf16* xnh   = (bf16*)alloc((long)MPAD * 512 * 2);
    bf16* xnl   = (bf16*)alloc((long)MPAD * 512 * 2);
    bf16* hgh   = (bf16*)alloc((long)MPAD * 2048 * 2);
    bf16* hgl   = (bf16*)alloc((long)MPAD * 2048 * 2);
    float* sinb = (float*)alloc(196l * 32 * 4);
    float* cosb = (float*)alloc(196l * 32 * 4);
    bf16* pwh   = (bf16*)alloc(512l * 512 * 2);
    bf16* pwl   = (bf16*)alloc(512l * 512 * 2);
    bf16* owh   = (bf16*)alloc(384l * 512 * 2);
    bf16* owl   = (bf16*)alloc(384l * 512 * 2);
    // union region (104.9 MB): {qkvb f32 | S | aoh | aol} vs {h1 f32 [6400][4096]} vs {patches hi/lo} vs {jn hi/lo}
    char* U     = (char*)alloc(104857600);
    float* qkvb = (float*)U;                           // [6400][1536] f32 (0 .. 39,321,600)
    float* S    = (float*)(U + 39321600);              // [16][24][3160] f32 (ends 44,175,360)
    bf16* aoh   = (bf16*)(U + 44175360);               // [6400][512] (ends 50,728,960)
    bf16* aol   = (bf16*)(U + 50728960);               // [6400][512] (ends 57,282,560)
    float* h1   = (float*)U;                           // [6400][4096] f32 = 104,857,600 B (ff1..gate only)
    bf16* ph    = (bf16*)U;                            // patches (setup only)
    bf16* pl    = (bf16*)(U + 6553600);
    bf16* jnh   = (bf16*)U;                            // [128][512] (final only)
    bf16* jnl   = (bf16*)(U + 131072);

    // ---- weight storage: persistent if workspace allows, else per-layer staging
    size_t base_off = off;
    bool persist = ws_size >= base_off + 202000000;    // need ~201.3 MB more
    bf16 *qkvWh, *qkvWl, *aoWh, *aoWl, *f1Wh, *f1Wl, *f2Wh, *f2Wl;
    long sz_qkv = 1536l * 512, sz_ao = 512l * 512, sz_f1 = 4096l * 512, sz_f2 = 512l * 2048;
    if (persist) {
        qkvWh = (bf16*)alloc(12 * sz_qkv * 2); qkvWl = (bf16*)alloc(12 * sz_qkv * 2);
        aoWh  = (bf16*)alloc(12 * sz_ao * 2);  aoWl  = (bf16*)alloc(12 * sz_ao * 2);
        f1Wh  = (bf16*)alloc(12 * sz_f1 * 2);  f1Wl  = (bf16*)alloc(12 * sz_f1 * 2);
        f2Wh  = (bf16*)alloc(12 * sz_f2 * 2);  f2Wl  = (bf16*)alloc(12 * sz_f2 * 2);
    } else {
        qkvWh = (bf16*)alloc(sz_qkv * 2); qkvWl = (bf16*)alloc(sz_qkv * 2);
        aoWh  = (bf16*)alloc(sz_ao * 2);  aoWl  = (bf16*)alloc(sz_ao * 2);
        f1Wh  = (bf16*)alloc(sz_f1 * 2);  f1Wl  = (bf16*)alloc(sz_f1 * 2);
        f2Wh  = (bf16*)alloc(sz_f2 * 2);  f2Wl  = (bf16*)alloc(sz_f2 * 2);
    }

    // ---- setup
    if (persist) {
        transpose_w<<<dim3(48, 16, 12), 256, 0, stream>>>(qkv_w, qkvWh, qkvWl, 512, 1536);
        transpose_w<<<dim3(16, 16, 12), 256, 0, stream>>>(attn_out_w, aoWh, aoWl, 512, 512);
        transpose_w<<<dim3(128, 16, 12), 256, 0, stream>>>(ff1_w, f1Wh, f1Wl, 512, 4096);
        transpose_w<<<dim3(16, 64, 12), 256, 0, stream>>>(ff2_w, f2Wh, f2Wl, 2048, 512);
    }
    transpose_w<<<dim3(16, 16, 1), 256, 0, stream>>>(patch_w, pwh, pwl, 512, 512);
    transpose_w<<<dim3(12, 16, 1), 256, 0, stream>>>(out_w, owh, owl, 512, 384);
    patchify<<<12800, 256, 0, stream>>>(video, ph, pl);
    xinit<<<96, 256, 0, stream>>>(joints_token, x);
    sincos_k<<<25, 256, 0, stream>>>(sinb, cosb);
    gemm3_bt<3><<<dim3(4, 49), 256, 0, stream>>>(ph, pl, pwh, pwl, patch_b, x, 6272, 512, 512, 6272);

    for (int l = 0; l < 12; ++l) {
        long lq = persist ? l * sz_qkv : 0, la = persist ? l * sz_ao : 0;
        long l1 = persist ? l * sz_f1 : 0, l2 = persist ? l * sz_f2 : 0;
        if (!persist) {
            transpose_w<<<dim3(48, 16, 1), 256, 0, stream>>>(qkv_w + l * sz_qkv, qkvWh, qkvWl, 512, 1536);
            transpose_w<<<dim3(16, 16, 1), 256, 0, stream>>>(attn_out_w + l * sz_ao, aoWh, aoWl, 512, 512);
            transpose_w<<<dim3(128, 16, 1), 256, 0, stream>>>(ff1_w + l * sz_f1, f1Wh, f1Wl, 512, 4096);
            transpose_w<<<dim3(16, 64, 1), 256, 0, stream>>>(ff2_w + l * sz_f2, f2Wh, f2Wl, 2048, 512);
        }
        ln_kernel<<<1600, 256, 0, stream>>>(x, ln_attn_w + l * 512, ln_attn_b + l * 512, xnh, xnl, MROWS, 0);
        gemm3_bt<0><<<dim3(12, 50), 256, 0, stream>>>(xnh, xnl, qkvWh + lq, qkvWl + lq, nullptr, qkvb, MPAD, 1536, 512, MPAD);
        jattn_scores<<<dim3(50, 16), 256, 0, stream>>>(qkvb, S);
        jattn_softmax<<<384, 256, 0, stream>>>(S);
        jattn_out<<<dim3(24, 16), 256, 0, stream>>>(qkvb, S, aoh, aol);
        frame_attn<<<dim3(16, 16), 256, 0, stream>>>(qkvb, sinb, cosb, aoh, aol);
        gemm3_bt<2><<<dim3(4, 50), 256, 0, stream>>>(aoh, aol, aoWh + la, aoWl + la, attn_out_b + l * 512, x, MPAD, 512, 512, MROWS);
        ln_kernel<<<1600, 256, 0, stream>>>(x, ln_ff_w + l * 512, ln_ff_b + l * 512, xnh, xnl, MROWS, 0);
        gemm3_bt<0><<<dim3(32, 50), 256, 0, stream>>>(xnh, xnl, f1Wh + l1, f1Wl + l1, ff1_b + l * 4096, h1, MPAD, 4096, 512, MPAD);
        gate_kernel<<<12800, 256, 0, stream>>>(h1, hgh, hgl);
        gemm3_bt<2><<<dim3(4, 50), 256, 0, stream>>>(hgh, hgl, f2Wh + l2, f2Wl + l2, ff2_b + l * 512, x, MPAD, 512, 2048, MROWS);
    }
    ln_kernel<<<32, 256, 0, stream>>>(x, ln_out_w, ln_out_b, jnh, jnl, 48, 1);
    gemm3_bt<0><<<dim3(3, 1), 256, 0, stream>>>(jnh, jnl, owh, owl, out_b, out, 128, 384, 512, 48);
    (void)in_sizes; (void)n_in; (void)out_size;
}

// Round 3
// 5926.902 us; speedup vs baseline: 1.3160x; 1.0999x over previous
//
#include <hip/hip_runtime.h>

typedef __bf16 bf16;
typedef short s8v  __attribute__((ext_vector_type(8)));
typedef short s4v  __attribute__((ext_vector_type(4)));
typedef float f4v  __attribute__((ext_vector_type(4)));
typedef bf16  bf8v __attribute__((ext_vector_type(8)));
typedef bf16  bf4v __attribute__((ext_vector_type(4)));

#define NTOK 3160      // 24 joints + 16*196 frame tokens
#define MROWS 6320     // 2*NTOK
#define MPAD  6400

__device__ __forceinline__ float bf2f(short v) {
    return __uint_as_float(((unsigned)(unsigned short)v) << 16);
}
__device__ __forceinline__ void split2(float v, bf16* hi, bf16* lo) {
    bf16 h = (bf16)v;
    *hi = h;
    *lo = (bf16)(v - (float)h);
}

// ---------------------------------------------------------------- transpose W (f32 KxN -> bf16 hi/lo NxK)
// perm=1: ff1 column interleave so (a_j, g_j) pairs are adjacent 16-col groups:
//   orig n < 2048 (a):  new = (n>>4)*32 + (n&15)
//   orig n >= 2048 (g): new = ((n-2048)>>4)*32 + 16 + (n&15)
__global__ void transpose_w(const float* __restrict__ W, bf16* __restrict__ Wth,
                            bf16* __restrict__ Wtl, int K_, int N_, int perm) {
    __shared__ float tile[32][33];
    int l = blockIdx.z;
    const float* Ws = W + (long)l * K_ * N_;
    long obase = (long)l * K_ * N_;
    int n0 = blockIdx.x * 32, k0 = blockIdx.y * 32;
    int tx = threadIdx.x & 31, ty = threadIdx.x >> 5;   // 32 x 8
    #pragma unroll
    for (int i = 0; i < 32; i += 8)
        tile[ty + i][tx] = Ws[(long)(k0 + ty + i) * N_ + n0 + tx];
    __syncthreads();
    #pragma unroll
    for (int i = 0; i < 32; i += 8) {
        int n = n0 + ty + i;
        int nn = perm ? (((n & 2047) >> 4) * 32 + (n & 15) + (((n >> 11) & 1) << 4)) : n;
        long oidx = obase + (long)nn * K_ + k0 + tx;
        split2(tile[tx][ty + i], Wth + oidx, Wtl + oidx);
    }
}

// ---------------------------------------------------------------- patchify: video -> patches hi/lo [6400][512]
__global__ void patchify(const float* __restrict__ video, bf16* __restrict__ ph,
                         bf16* __restrict__ pl) {
    int idx = blockIdx.x * 256 + threadIdx.x;          // over 6400*512
    int row = idx >> 9, fc = idx & 511;
    if (row >= 6272) { ph[idx] = (bf16)0.f; pl[idx] = (bf16)0.f; return; }
    int bi = row / 3136, t = row % 3136;
    int fi = t / 196, pp = t % 196, hp_i = pp / 14, wp_i = pp % 14;
    int phh = fc >> 5, pw = (fc >> 1) & 15, c = fc & 1;
    long vidx = ((((long)(bi * 16 + fi) * 2 + c) * 224) + hp_i * 16 + phh) * 224 + wp_i * 16 + pw;
    split2(video[vidx], ph + idx, pl + idx);
}

// ---------------------------------------------------------------- x joint-token init
__global__ void xinit(const float* __restrict__ jt, float* __restrict__ x) {
    int idx = blockIdx.x * 256 + threadIdx.x;          // over 2*24*512
    int b = idx / (24 * 512), r = idx % (24 * 512);
    x[(long)b * NTOK * 512 + r] = jt[r];
}

// ---------------------------------------------------------------- axial rotary tables [196][32]
__global__ void sincos_k(float* __restrict__ sinb, float* __restrict__ cosb) {
    int idx = blockIdx.x * 256 + threadIdx.x;
    if (idx >= 196 * 32) return;
    int p = idx >> 5, i = idx & 31;
    int hp_i = p / 14, wp_i = p % 14;
    float coord = (i < 16) ? (-1.f + 2.f * hp_i / 13.f) : (-1.f + 2.f * wp_i / 13.f);
    int si = i & 15;
    float scale = exp2f(si * (float)(2.3219280948873623 / 15.0)); // 2^linspace(0,log2(5),16)
    float ang = coord * scale * 3.14159265358979323846f;
    sinb[idx] = sinf(ang);
    cosb[idx] = cosf(ang);
}

// ---------------------------------------------------------------- LayerNorm fp32 -> bf16 hi/lo (wave per row)
__global__ void ln_kernel(const float* __restrict__ x, const float* __restrict__ w,
                          const float* __restrict__ bb, bf16* __restrict__ oh,
                          bf16* __restrict__ ol, int nreal, int jmap) {
    int row = blockIdx.x * 4 + (threadIdx.x >> 6);
    int lane = threadIdx.x & 63;
    if (row >= nreal) {
        bf8v z;
        #pragma unroll
        for (int i = 0; i < 8; ++i) z[i] = (bf16)0.f;
        *(bf8v*)(oh + (long)row * 512 + lane * 8) = z;
        *(bf8v*)(ol + (long)row * 512 + lane * 8) = z;
        return;
    }
    long src = jmap ? ((long)(row / 24) * NTOK + row % 24) : row;
    const float* xr = x + src * 512 + lane * 8;
    f4v a = *(const f4v*)xr;
    f4v b4 = *(const f4v*)(xr + 4);
    float s = 0.f, sq = 0.f;
    #pragma unroll
    for (int i = 0; i < 4; ++i) { s += a[i] + b4[i]; sq += a[i]*a[i] + b4[i]*b4[i]; }
    #pragma unroll
    for (int off = 32; off; off >>= 1) { s += __shfl_xor(s, off); sq += __shfl_xor(sq, off); }
    float mean = s * (1.f / 512.f);
    float var = sq * (1.f / 512.f) - mean * mean;
    float r = rsqrtf(var + 1e-5f);
    f4v wv0 = *(const f4v*)(w + lane * 8),  wv1 = *(const f4v*)(w + lane * 8 + 4);
    f4v bv0 = *(const f4v*)(bb + lane * 8), bv1 = *(const f4v*)(bb + lane * 8 + 4);
    bf8v vh, vl;
    #pragma unroll
    for (int i = 0; i < 4; ++i) {
        float v0 = (a[i]  - mean) * r * wv0[i] + bv0[i];
        float v1 = (b4[i] - mean) * r * wv1[i] + bv1[i];
        bf16 h0 = (bf16)v0, h1_ = (bf16)v1;
        vh[i] = h0;     vl[i] = (bf16)(v0 - (float)h0);
        vh[i + 4] = h1_; vl[i + 4] = (bf16)(v1 - (float)h1_);
    }
    *(bf8v*)(oh + (long)row * 512 + lane * 8) = vh;
    *(bf8v*)(ol + (long)row * 512 + lane * 8) = vl;
}

// ---------------------------------------------------------------- split-bf16 MFMA GEMM: C = A*B with A=Ah+Al, B=Bh+Bl
// 3-term: Ah*Bh + Ah*Bl + Al*Bh; fp32 accumulate -> ~fp32-accurate.
// EPI: 0 = f32 out (+bias)
//      1 = fused gated-GELU (ff1, permuted cols): a=acc[.][even], g=acc[.][odd];
//          writes bf16 hi/lo to oH/oL at [row][2048] pair index = orig a-col
//      2 = residual add into f32 x[.][512]
//      3 = patch row-remap into x
template<int EPI>
__global__ __launch_bounds__(256)
void gemm3_bt(const bf16* __restrict__ Ah, const bf16* __restrict__ Al,
              const bf16* __restrict__ Bh, const bf16* __restrict__ Bl,
              const float* __restrict__ bias, float* __restrict__ outF,
              bf16* __restrict__ oH, bf16* __restrict__ oL,
              int M, int N, int K, int Mstore) {
    __shared__ bf16 LAh[128 * 32];
    __shared__ bf16 LAl[128 * 32];
    __shared__ bf16 LBh[128 * 32];
    __shared__ bf16 LBl[128 * 32];
    int tid = threadIdx.x;
    int wave = tid >> 6, lane = tid & 63;
    long m0 = (long)blockIdx.y * 128;
    long n0 = (long)blockIdx.x * 128;
    int wm = (wave >> 1) * 64, wn = (wave & 1) * 64;
    f4v acc[4][4] = {};
    int r16 = lane & 15, q4 = lane >> 4;
    int srow = lane >> 2;          // row within 16-row slab (identity mapping)
    int cg = lane & 3;             // chunk within 32-col row (identity mapping)

    const bf16* Agh = Ah + m0 * K;
    const bf16* Agl = Al + m0 * K;
    const bf16* Bgh = Bh + n0 * K;
    const bf16* Bgl = Bl + n0 * K;

    for (int kb = 0; kb < K; kb += 32) {
        #pragma unroll
        for (int ss = 0; ss < 2; ++ss) {
            int s = wave * 2 + ss;
            long roff = (long)(s * 16 + srow) * K + kb + cg * 8;
            int ldso = s * 512;   // elements
            __builtin_amdgcn_global_load_lds(
                (const __attribute__((address_space(1))) void*)(Agh + roff),
                (__attribute__((address_space(3))) void*)(LAh + ldso), 16, 0, 0);
            __builtin_amdgcn_global_load_lds(
                (const __attribute__((address_space(1))) void*)(Agl + roff),
                (__attribute__((address_space(3))) void*)(LAl + ldso), 16, 0, 0);
            __builtin_amdgcn_global_load_lds(
                (const __attribute__((address_space(1))) void*)(Bgh + roff),
                (__attribute__((address_space(3))) void*)(LBh + ldso), 16, 0, 0);
            __builtin_amdgcn_global_load_lds(
                (const __attribute__((address_space(1))) void*)(Bgl + roff),
                (__attribute__((address_space(3))) void*)(LBl + ldso), 16, 0, 0);
        }
        __syncthreads();
        s8v ah[4], al[4], bh[4], bl[4];
        #pragma unroll
        for (int mb = 0; mb < 4; ++mb) {
            int off = (wm + mb * 16 + r16) * 32 + q4 * 8;
            ah[mb] = *(const s8v*)(LAh + off);
            al[mb] = *(const s8v*)(LAl + off);
        }
        #pragma unroll
        for (int nb = 0; nb < 4; ++nb) {
            int off = (wn + nb * 16 + r16) * 32 + q4 * 8;
            bh[nb] = *(const s8v*)(LBh + off);
            bl[nb] = *(const s8v*)(LBl + off);
        }
        #pragma unroll
        for (int mb = 0; mb < 4; ++mb)
            #pragma unroll
            for (int nb = 0; nb < 4; ++nb) {
                acc[mb][nb] = __builtin_amdgcn_mfma_f32_16x16x32_bf16(ah[mb], bh[nb], acc[mb][nb], 0, 0, 0);
                acc[mb][nb] = __builtin_amdgcn_mfma_f32_16x16x32_bf16(ah[mb], bl[nb], acc[mb][nb], 0, 0, 0);
                acc[mb][nb] = __builtin_amdgcn_mfma_f32_16x16x32_bf16(al[mb], bh[nb], acc[mb][nb], 0, 0, 0);
            }
        __syncthreads();
    }
    if (EPI == 1) {
        #pragma unroll
        for (int np = 0; np < 2; ++np) {
            int colA = (int)n0 + wn + np * 32 + r16;       // a-subtile col (nb = np*2, offset nb*16)
            int pcol = ((colA >> 5) << 4) + (colA & 15);   // pair idx == orig a-col (0..2047)
            float ba = bias[pcol], bg = bias[pcol + 2048];
            #pragma unroll
            for (int mb = 0; mb < 4; ++mb)
                #pragma unroll
                for (int i = 0; i < 4; ++i) {
                    long row = m0 + wm + mb * 16 + q4 * 4 + i;
                    if (row >= Mstore) continue;
                    float a = acc[mb][np * 2][i] + ba;
                    float g = acc[mb][np * 2 + 1][i] + bg;
                    float gl = 0.5f * g * (1.f + erff(g * 0.70710678118654752f));
                    float v = a * gl;
                    long oidx = row * 2048 + pcol;
                    split2(v, oH + oidx, oL + oidx);
                }
        }
    } else {
        #pragma unroll
        for (int nb = 0; nb < 4; ++nb) {
            int col = (int)n0 + wn + nb * 16 + r16;
            float bv = bias ? bias[col] : 0.f;
            #pragma unroll
            for (int mb = 0; mb < 4; ++mb) {
                #pragma unroll
                for (int i = 0; i < 4; ++i) {
                    long row = m0 + wm + mb * 16 + q4 * 4 + i;
                    if (row >= Mstore) continue;
                    float v = acc[mb][nb][i] + bv;
                    if (EPI == 0) outF[row * N + col] = v;
                    else if (EPI == 2) outF[row * 512 + col] += v;
                    else {  // EPI == 3: rows are b*3136+t -> x row b*3160 + 24 + t
                        long orow = row + 24 * (row / 3136 + 1);
                        outF[orow * 512 + col] = v;
                    }
                }
            }
        }
    }
    (void)M;
}

// ---------------------------------------------------------------- joints attention: S = (jq*scale) @ k^T over all 3160 keys
__global__ void jattn_scores(const float* __restrict__ qkv, float* __restrict__ S) {
    int kt = blockIdx.x, bh = blockIdx.y;
    int b = bh >> 3, h = bh & 7;
    long rowbase = (long)b * NTOK;
    __shared__ float qs[24][64];
    __shared__ float ks[64][65];
    int tid = threadIdx.x;
    for (int idx = tid; idx < 24 * 64; idx += 256) {
        int j = idx >> 6, d = idx & 63;
        qs[j][d] = qkv[(rowbase + j) * 1536 + h * 64 + d] * 0.125f;
    }
    for (int idx = tid; idx < 64 * 64; idx += 256) {
        int j = idx >> 6, d = idx & 63;
        int tok = kt * 64 + j;
        ks[j][d] = (tok < NTOK) ? qkv[(rowbase + tok) * 1536 + 512 + h * 64 + d] : 0.f;
    }
    __syncthreads();
    for (int idx = tid; idx < 24 * 64; idx += 256) {
        int qi = idx >> 6, kk = idx & 63;
        int tok = kt * 64 + kk;
        if (tok >= NTOK) continue;
        float acc = 0.f;
        #pragma unroll 8
        for (int d = 0; d < 64; ++d) acc += qs[qi][d] * ks[kk][d];
        S[((long)bh * 24 + qi) * NTOK + tok] = acc;
    }
}

__global__ void jattn_softmax(float* __restrict__ S) {
    int r = blockIdx.x;                      // 0..383
    float* row = S + (long)r * NTOK;
    int tid = threadIdx.x, wave = tid >> 6, lane = tid & 63;
    __shared__ float wred[4];
    float m = -3e38f;
    for (int i = tid; i < NTOK; i += 256) m = fmaxf(m, row[i]);
    #pragma unroll
    for (int off = 32; off; off >>= 1) m = fmaxf(m, __shfl_xor(m, off));
    if (lane == 0) wred[wave] = m;
    __syncthreads();
    m = fmaxf(fmaxf(wred[0], wred[1]), fmaxf(wred[2], wred[3]));
    __syncthreads();
    float s = 0.f;
    for (int i = tid; i < NTOK; i += 256) { float e = __expf(row[i] - m); row[i] = e; s += e; }
    #pragma unroll
    for (int off = 32; off; off >>= 1) s += __shfl_xor(s, off);
    if (lane == 0) wred[wave] = s;
    __syncthreads();
    s = wred[0] + wred[1] + wred[2] + wred[3];
    float inv = 1.f / s;
    for (int i = tid; i < NTOK; i += 256) row[i] *= inv;
}

// ---------------------------------------------------------------- joints PV: grid (8 key-chunks, 16 bh)
// Stage P chunk [395][24] in LDS (pad 28 for 16B-aligned f4v reads), each wave
// accumulates all 24 queries per V-row load; deterministic per-chunk partials.
__global__ __launch_bounds__(256)
void jattn_pv(const float* __restrict__ qkv, const float* __restrict__ S,
              float* __restrict__ jo4) {
    int kc = blockIdx.x, bh = blockIdx.y;
    int b = bh >> 3, h = bh & 7;
    long rowbase = (long)b * NTOK;
    int kbase = kc * 395;                    // 3160 = 8 * 395
    __shared__ __align__(16) float LsT[395][28];
    __shared__ float ob[4][24][64];
    int tid = threadIdx.x, w = tid >> 6, lane = tid & 63;
    for (int q = 0; q < 24; ++q) {
        const float* Pr = S + ((long)bh * 24 + q) * NTOK + kbase;
        for (int jj = tid; jj < 395; jj += 256) LsT[jj][q] = Pr[jj];
    }
    __syncthreads();
    float o[24] = {};
    for (int jj = w; jj < 395; jj += 4) {
        float v = qkv[(rowbase + kbase + jj) * 1536 + 1024 + h * 64 + lane];
        #pragma unroll
        for (int q = 0; q < 24; q += 4) {
            f4v p = *(const f4v*)&LsT[jj][q];
            o[q]     += p[0] * v;
            o[q + 1] += p[1] * v;
            o[q + 2] += p[2] * v;
            o[q + 3] += p[3] * v;
        }
    }
    #pragma unroll
    for (int q = 0; q < 24; ++q) ob[w][q][lane] = o[q];
    __syncthreads();
    for (int idx = tid; idx < 24 * 64; idx += 256) {
        int q = idx >> 6, d = idx & 63;
        jo4[(((long)kc * 16 + bh) * 24 + q) * 64 + d] =
            ob[0][q][d] + ob[1][q][d] + ob[2][q][d] + ob[3][q][d];
    }
}

__global__ void jattn_fin(const float* __restrict__ jo4, bf16* __restrict__ aoh,
                          bf16* __restrict__ aol) {
    int idx = blockIdx.x * 256 + threadIdx.x;  // over 16*24*64 = 24576
    if (idx >= 16 * 24 * 64) return;
    int bh = idx / 1536, r = idx % 1536;       // per-bh span = 24*64 = 1536
    int b = bh >> 3, h = bh & 7;
    int q = r >> 6, d = r & 63;
    float s = 0.f;
    #pragma unroll
    for (int kc = 0; kc < 8; ++kc)
        s += jo4[(((long)kc * 16 + bh) * 24 + q) * 64 + d];
    long oidx = ((long)b * NTOK + q) * 512 + h * 64 + d;
    split2(s, aoh + oidx, aol + oidx);
}

// ---------------------------------------------------------------- frame attention, MFMA version
__global__ __launch_bounds__(256, 1)
void frame_attn(const float* __restrict__ qkv, const float* __restrict__ sinb,
                const float* __restrict__ cosb, bf16* __restrict__ aoh,
                bf16* __restrict__ aol) {
    int fr = blockIdx.x, bh = blockIdx.y;
    int b = bh >> 3, h = bh & 7;
    long rowbase = (long)b * NTOK;
    int t0 = 24 + fr * 196;

    __shared__ __align__(16) bf16 Ks[224 * 64];     // 28672 B
    __shared__ __align__(16) bf16 Qh[224 * 64];     // 28672
    __shared__ __align__(16) bf16 Ql[224 * 64];     // 28672
    __shared__ __align__(16) bf16 Vh[64 * 224];     // 28672
    __shared__ __align__(16) bf16 Vl[64 * 224];     // 28672
    __shared__ __align__(16) bf16 Ph[4 * 16 * 64];  // 8192
    __shared__ __align__(16) bf16 Pl[4 * 16 * 64];  // 8192  => total 159744 B

    int tid = threadIdx.x;
    for (int idx = tid; idx < 224 * 16; idx += 256) {
        int j = idx >> 4, d4 = idx & 15;
        int tok = (j < 24) ? j : (t0 + j - 24);
        bf4v kb;
        if (j < 220) {
            f4v kv = *(const f4v*)(qkv + (rowbase + tok) * 1536 + 512 + h * 64 + d4 * 4);
            if (j >= 24) {
                int pos = j - 24;
                float sn0 = sinb[pos * 32 + d4 * 2],     cs0 = cosb[pos * 32 + d4 * 2];
                float sn1 = sinb[pos * 32 + d4 * 2 + 1], cs1 = cosb[pos * 32 + d4 * 2 + 1];
                kb[0] = (bf16)(kv[0] * cs0 - kv[1] * sn0);
                kb[1] = (bf16)(kv[1] * cs0 + kv[0] * sn0);
                kb[2] = (bf16)(kv[2] * cs1 - kv[3] * sn1);
                kb[3] = (bf16)(kv[3] * cs1 + kv[2] * sn1);
            } else {
                kb[0] = (bf16)kv[0]; kb[1] = (bf16)kv[1];
                kb[2] = (bf16)kv[2]; kb[3] = (bf16)kv[3];
            }
        } else {
            kb[0] = kb[1] = kb[2] = kb[3] = (bf16)0.f;
        }
        *(bf4v*)((char*)Ks + ((j * 128 + d4 * 8) ^ ((j & 7) << 4))) = kb;
        bf4v qhv, qlv;
        if (j < 196) {
            f4v qv = *(const f4v*)(qkv + (rowbase + t0 + j) * 1536 + h * 64 + d4 * 4);
            float sn0 = sinb[j * 32 + d4 * 2],     cs0 = cosb[j * 32 + d4 * 2];
            float sn1 = sinb[j * 32 + d4 * 2 + 1], cs1 = cosb[j * 32 + d4 * 2 + 1];
            float r0 = (qv[0] * cs0 - qv[1] * sn0) * 0.125f;
            float r1 = (qv[1] * cs0 + qv[0] * sn0) * 0.125f;
            float r2 = (qv[2] * cs1 - qv[3] * sn1) * 0.125f;
            float r3 = (qv[3] * cs1 + qv[2] * sn1) * 0.125f;
            bf16 h0 = (bf16)r0; qhv[0] = h0; qlv[0] = (bf16)(r0 - (float)h0);
            bf16 h1 = (bf16)r1; qhv[1] = h1; qlv[1] = (bf16)(r1 - (float)h1);
            bf16 h2 = (bf16)r2; qhv[2] = h2; qlv[2] = (bf16)(r2 - (float)h2);
            bf16 h3 = (bf16)r3; qhv[3] = h3; qlv[3] = (bf16)(r3 - (float)h3);
        } else {
            qhv[0] = qhv[1] = qhv[2] = qhv[3] = (bf16)0.f;
            qlv[0] = qlv[1] = qlv[2] = qlv[3] = (bf16)0.f;
        }
        int qoff = (j * 128 + d4 * 8) ^ ((j & 7) << 4);
        *(bf4v*)((char*)Qh + qoff) = qhv;
        *(bf4v*)((char*)Ql + qoff) = qlv;
        f4v vv = {0.f, 0.f, 0.f, 0.f};
        if (j < 220)
            vv = *(const f4v*)(qkv + (rowbase + tok) * 1536 + 1024 + h * 64 + d4 * 4);
        #pragma unroll
        for (int k = 0; k < 4; ++k) {
            int d = d4 * 4 + k;
            int vo = (d * 448 + j * 2) ^ ((d & 3) << 4);
            bf16 hv = (bf16)vv[k];
            *(bf16*)((char*)Vh + vo) = hv;
            *(bf16*)((char*)Vl + vo) = (bf16)(vv[k] - (float)hv);
        }
    }
    __syncthreads();

    int w = tid >> 6, lane = tid & 63;
    int r16 = lane & 15, q4 = lane >> 4;
    char* PhB = (char*)Ph + w * 2048;
    char* PlB = (char*)Pl + w * 2048;
    int nt = (w == 3) ? 2 : 4;

    for (int jt = 0; jt < nt; ++jt) {
        int qt = w * 4 + jt;
        int qrow = qt * 16 + r16;
        int qsw = (qrow & 7) << 4;
        s8v ah0 = *(const s8v*)((char*)Qh + ((qrow * 128 + q4 * 16) ^ qsw));
        s8v ah1 = *(const s8v*)((char*)Qh + ((qrow * 128 + 64 + q4 * 16) ^ qsw));
        s8v al0 = *(const s8v*)((char*)Ql + ((qrow * 128 + q4 * 16) ^ qsw));
        s8v al1 = *(const s8v*)((char*)Ql + ((qrow * 128 + 64 + q4 * 16) ^ qsw));
        f4v s[14];
        #pragma unroll
        for (int kt = 0; kt < 14; ++kt) {
            int krow = kt * 16 + r16;
            int ksw = (krow & 7) << 4;
            s8v b0 = *(const s8v*)((char*)Ks + ((krow * 128 + q4 * 16) ^ ksw));
            s8v b1 = *(const s8v*)((char*)Ks + ((krow * 128 + 64 + q4 * 16) ^ ksw));
            f4v a = {0.f, 0.f, 0.f, 0.f};
            a = __builtin_amdgcn_mfma_f32_16x16x32_bf16(ah0, b0, a, 0, 0, 0);
            a = __builtin_amdgcn_mfma_f32_16x16x32_bf16(ah1, b1, a, 0, 0, 0);
            a = __builtin_amdgcn_mfma_f32_16x16x32_bf16(al0, b0, a, 0, 0, 0);
            a = __builtin_amdgcn_mfma_f32_16x16x32_bf16(al1, b1, a, 0, 0, 0);
            s[kt] = a;
        }
        if (r16 >= 12) { s[13][0] = -3e38f; s[13][1] = -3e38f; s[13][2] = -3e38f; s[13][3] = -3e38f; }
        f4v m = s[0];
        #pragma unroll
        for (int kt = 1; kt < 14; ++kt)
            #pragma unroll
            for (int i = 0; i < 4; ++i) m[i] = fmaxf(m[i], s[kt][i]);
        #pragma unroll
        for (int off = 1; off <= 8; off <<= 1)
            #pragma unroll
            for (int i = 0; i < 4; ++i) m[i] = fmaxf(m[i], __shfl_xor(m[i], off));
        f4v sum = {0.f, 0.f, 0.f, 0.f};
        #pragma unroll
        for (int kt = 0; kt < 14; ++kt)
            #pragma unroll
            for (int i = 0; i < 4; ++i) { s[kt][i] = __expf(s[kt][i] - m[i]); sum[i] += s[kt][i]; }
        #pragma unroll
        for (int off = 1; off <= 8; off <<= 1)
            #pragma unroll
            for (int i = 0; i < 4; ++i) sum[i] += __shfl_xor(sum[i], off);
        f4v inv;
        #pragma unroll
        for (int i = 0; i < 4; ++i) inv[i] = 1.f / sum[i];
        #pragma unroll
        for (int kt = 0; kt < 14; ++kt)
            #pragma unroll
            for (int i = 0; i < 4; ++i) s[kt][i] *= inv[i];

        f4v o[4] = {{0.f,0.f,0.f,0.f},{0.f,0.f,0.f,0.f},{0.f,0.f,0.f,0.f},{0.f,0.f,0.f,0.f}};
        #pragma unroll
        for (int ks = 0; ks < 7; ++ks) {
            #pragma unroll
            for (int half = 0; half < 2; ++half) {
                int kt = ks * 2 + half;
                #pragma unroll
                for (int i = 0; i < 4; ++i) {
                    int prow = q4 * 4 + i;
                    int pbyte = (prow * 128 + (half * 16 + r16) * 2) ^ ((prow & 7) << 4);
                    float p = s[kt][i];
                    bf16 hb = (bf16)p;
                    *(bf16*)(PhB + pbyte) = hb;
                    *(bf16*)(PlB + pbyte) = (bf16)(p - (float)hb);
                }
            }
            int abyte = (r16 * 128 + q4 * 16) ^ ((r16 & 7) << 4);
            s8v pah = *(const s8v*)(PhB + abyte);
            s8v pal = *(const s8v*)(PlB + abyte);
            #pragma unroll
            for (int dt = 0; dt < 4; ++dt) {
                int vrow = dt * 16 + r16;
                int vbyte = (vrow * 448 + ks * 64 + q4 * 16) ^ ((vrow & 3) << 4);
                s8v bvh = *(const s8v*)((char*)Vh + vbyte);
                s8v bvl = *(const s8v*)((char*)Vl + vbyte);
                o[dt] = __builtin_amdgcn_mfma_f32_16x16x32_bf16(pah, bvh, o[dt], 0, 0, 0);
                o[dt] = __builtin_amdgcn_mfma_f32_16x16x32_bf16(pal, bvh, o[dt], 0, 0, 0);
                o[dt] = __builtin_amdgcn_mfma_f32_16x16x32_bf16(pah, bvl, o[dt], 0, 0, 0);
            }
        }
        #pragma unroll
        for (int dt = 0; dt < 4; ++dt)
            #pragma unroll
            for (int i = 0; i < 4; ++i) {
                int query = qt * 16 + q4 * 4 + i;
                if (query < 196) {
                    long oidx = (rowbase + t0 + query) * 512 + h * 64 + dt * 16 + r16;
                    split2(o[dt][i], aoh + oidx, aol + oidx);
                }
            }
    }
}

// ----------------------------------------------------------------
extern "C" void kernel_launch(void* const* d_in, const int* in_sizes, int n_in,
                              void* d_out, int out_size, void* d_ws, size_t ws_size,
                              hipStream_t stream) {
    const float* video        = (const float*)d_in[0];
    const float* patch_w      = (const float*)d_in[1];
    const float* patch_b      = (const float*)d_in[2];
    const float* joints_token = (const float*)d_in[3];
    const float* ln_attn_w    = (const float*)d_in[4];
    const float* ln_attn_b    = (const float*)d_in[5];
    const float* qkv_w        = (const float*)d_in[6];
    const float* attn_out_w   = (const float*)d_in[7];
    const float* attn_out_b   = (const float*)d_in[8];
    const float* ln_ff_w      = (const float*)d_in[9];
    const float* ln_ff_b      = (const float*)d_in[10];
    const float* ff1_w        = (const float*)d_in[11];
    const float* ff1_b        = (const float*)d_in[12];
    const float* ff2_w        = (const float*)d_in[13];
    const float* ff2_b        = (const float*)d_in[14];
    const float* ln_out_w     = (const float*)d_in[15];
    const float* ln_out_b     = (const float*)d_in[16];
    const float* out_w        = (const float*)d_in[17];
    const float* out_b        = (const float*)d_in[18];
    float* out = (float*)d_out;

    char* ws = (char*)d_ws;
    size_t off = 0;
    auto alloc = [&](size_t bytes) { void* p = ws + off; off += (bytes + 255) & ~(size_t)255; return p; };

    // ---- common buffers
    float* x    = (float*)alloc((long)MPAD * 512 * 4);
    bf16* xnh   = (bf16*)alloc((long)MPAD * 512 * 2);
    bf16* xnl   = (bf16*)alloc((long)MPAD * 512 * 2);
    bf16* hgh   = (bf16*)alloc((long)MPAD * 2048 * 2);
    bf16* hgl   = (bf16*)alloc((long)MPAD * 2048 * 2);
    float* sinb = (float*)alloc(196l * 32 * 4);
    float* cosb = (float*)alloc(196l * 32 * 4);
    bf16* pwh   = (bf16*)alloc(512l * 512 * 2);
    bf16* pwl   = (bf16*)alloc(512l * 512 * 2);
    bf16* owh   = (bf16*)alloc(384l * 512 * 2);
    bf16* owl   = (bf16*)alloc(384l * 512 * 2);
    // union region (104.9 MB): {qkvb f32 | S | aoh | aol | jo4} vs {patches hi/lo} vs {jn hi/lo}
    char* U     = (char*)alloc(104857600);
    float* qkvb = (float*)U;                           // [6400][1536] f32 (0 .. 39,321,600)
    float* S    = (float*)(U + 39321600);              // [16][24][3160] f32 (ends 44,175,360)
    bf16* aoh   = (bf16*)(U + 44175360);               // [6400][512] (ends 50,728,960)
    bf16* aol   = (bf16*)(U + 50728960);               // [6400][512] (ends 57,282,560)
    float* jo4  = (float*)(U + 57282560);              // [8][16][24][64] f32 (ends 58,068,992)
    bf16* ph    = (bf16*)U;                            // patches (setup only)
    bf16* pl    = (bf16*)(U + 6553600);
    bf16* jnh   = (bf16*)U;                            // [128][512] (final only)
    bf16* jnl   = (bf16*)(U + 131072);

    // ---- weight storage: persistent if workspace allows, else per-layer staging
    size_t base_off = off;
    bool persist = ws_size >= base_off + 202000000;    // need ~201.3 MB more
    bf16 *qkvWh, *qkvWl, *aoWh, *aoWl, *f1Wh, *f1Wl, *f2Wh, *f2Wl;
    long sz_qkv = 1536l * 512, sz_ao = 512l * 512, sz_f1 = 4096l * 512, sz_f2 = 512l * 2048;
    if (persist) {
        qkvWh = (bf16*)alloc(12 * sz_qkv * 2); qkvWl = (bf16*)alloc(12 * sz_qkv * 2);
        aoWh  = (bf16*)alloc(12 * sz_ao * 2);  aoWl  = (bf16*)alloc(12 * sz_ao * 2);
        f1Wh  = (bf16*)alloc(12 * sz_f1 * 2);  f1Wl  = (bf16*)alloc(12 * sz_f1 * 2);
        f2Wh  = (bf16*)alloc(12 * sz_f2 * 2);  f2Wl  = (bf16*)alloc(12 * sz_f2 * 2);
    } else {
        qkvWh = (bf16*)alloc(sz_qkv * 2); qkvWl = (bf16*)alloc(sz_qkv * 2);
        aoWh  = (bf16*)alloc(sz_ao * 2);  aoWl  = (bf16*)alloc(sz_ao * 2);
        f1Wh  = (bf16*)alloc(sz_f1 * 2);  f1Wl  = (bf16*)alloc(sz_f1 * 2);
        f2Wh  = (bf16*)alloc(sz_f2 * 2);  f2Wl  = (bf16*)alloc(sz_f2 * 2);
    }

    // ---- setup
    if (persist) {
        transpose_w<<<dim3(48, 16, 12), 256, 0, stream>>>(qkv_w, qkvWh, qkvWl, 512, 1536, 0);
        transpose_w<<<dim3(16, 16, 12), 256, 0, stream>>>(attn_out_w, aoWh, aoWl, 512, 512, 0);
        transpose_w<<<dim3(128, 16, 12), 256, 0, stream>>>(ff1_w, f1Wh, f1Wl, 512, 4096, 1);
        transpose_w<<<dim3(16, 64, 12), 256, 0, stream>>>(ff2_w, f2Wh, f2Wl, 2048, 512, 0);
    }
    transpose_w<<<dim3(16, 16, 1), 256, 0, stream>>>(patch_w, pwh, pwl, 512, 512, 0);
    transpose_w<<<dim3(12, 16, 1), 256, 0, stream>>>(out_w, owh, owl, 512, 384, 0);
    patchify<<<12800, 256, 0, stream>>>(video, ph, pl);
    xinit<<<96, 256, 0, stream>>>(joints_token, x);
    sincos_k<<<25, 256, 0, stream>>>(sinb, cosb);
    gemm3_bt<3><<<dim3(4, 49), 256, 0, stream>>>(ph, pl, pwh, pwl, patch_b, x, nullptr, nullptr, 6272, 512, 512, 6272);

    for (int l = 0; l < 12; ++l) {
        long lq = persist ? l * sz_qkv : 0, la = persist ? l * sz_ao : 0;
        long l1 = persist ? l * sz_f1 : 0, l2 = persist ? l * sz_f2 : 0;
        if (!persist) {
            transpose_w<<<dim3(48, 16, 1), 256, 0, stream>>>(qkv_w + l * sz_qkv, qkvWh, qkvWl, 512, 1536, 0);
            transpose_w<<<dim3(16, 16, 1), 256, 0, stream>>>(attn_out_w + l * sz_ao, aoWh, aoWl, 512, 512, 0);
            transpose_w<<<dim3(128, 16, 1), 256, 0, stream>>>(ff1_w + l * sz_f1, f1Wh, f1Wl, 512, 4096, 1);
            transpose_w<<<dim3(16, 64, 1), 256, 0, stream>>>(ff2_w + l * sz_f2, f2Wh, f2Wl, 2048, 512, 0);
        }
        ln_kernel<<<1600, 256, 0, stream>>>(x, ln_attn_w + l * 512, ln_attn_b + l * 512, xnh, xnl, MROWS, 0);
        gemm3_bt<0><<<dim3(12, 50), 256, 0, stream>>>(xnh, xnl, qkvWh + lq, qkvWl + lq, nullptr, qkvb, nullptr, nullptr, MPAD, 1536, 512, MPAD);
        jattn_scores<<<dim3(50, 16), 256, 0, stream>>>(qkvb, S);
        jattn_softmax<<<384, 256, 0, stream>>>(S);
        jattn_pv<<<dim3(8, 16), 256, 0, stream>>>(qkvb, S, jo4);
        jattn_fin<<<96, 256, 0, stream>>>(jo4, aoh, aol);
        frame_attn<<<dim3(16, 16), 256, 0, stream>>>(qkvb, sinb, cosb, aoh, aol);
        gemm3_bt<2><<<dim3(4, 50), 256, 0, stream>>>(aoh, aol, aoWh + la, aoWl + la, attn_out_b + l * 512, x, nullptr, nullptr, MPAD, 512, 512, MROWS);
        ln_kernel<<<1600, 256, 0, stream>>>(x, ln_ff_w + l * 512, ln_ff_b + l * 512, xnh, xnl, MROWS, 0);
        gemm3_bt<1><<<dim3(32, 50), 256, 0, stream>>>(xnh, xnl, f1Wh + l1, f1Wl + l1, ff1_b + l * 4096, nullptr, hgh, hgl, MPAD, 4096, 512, MPAD);
        gemm3_bt<2><<<dim3(4, 50), 256, 0, stream>>>(hgh, hgl, f2Wh + l2, f2Wl + l2, ff2_b + l * 512, x, nullptr, nullptr, MPAD, 512, 2048, MROWS);
    }
    ln_kernel<<<32, 256, 0, stream>>>(x, ln_out_w, ln_out_b, jnh, jnl, 48, 1);
    gemm3_bt<0><<<dim3(3, 1), 256, 0, stream>>>(jnh, jnl, owh, owl, out_b, out, nullptr, nullptr, 128, 384, 512, 48);
    (void)in_sizes; (void)n_in; (void)out_size;
}

// Round 4
// 5039.399 us; speedup vs baseline: 1.5478x; 1.1761x over previous
//
#include <hip/hip_runtime.h>

typedef __bf16 bf16;
typedef short s8v  __attribute__((ext_vector_type(8)));
typedef short s4v  __attribute__((ext_vector_type(4)));
typedef float f4v  __attribute__((ext_vector_type(4)));
typedef bf16  bf8v __attribute__((ext_vector_type(8)));
typedef bf16  bf4v __attribute__((ext_vector_type(4)));

#define NTOK 3160      // 24 joints + 16*196 frame tokens
#define MROWS 6320     // 2*NTOK
#define MPAD  6400

__device__ __forceinline__ float bf2f(short v) {
    return __uint_as_float(((unsigned)(unsigned short)v) << 16);
}
__device__ __forceinline__ void split2(float v, bf16* hi, bf16* lo) {
    bf16 h = (bf16)v;
    *hi = h;
    *lo = (bf16)(v - (float)h);
}

// ---------------------------------------------------------------- transpose W (f32 KxN -> bf16 hi/lo NxK)
// perm=1: ff1 column interleave so (a_j, g_j) pairs are adjacent 16-col groups:
//   orig n < 2048 (a):  new = (n>>4)*32 + (n&15)
//   orig n >= 2048 (g): new = ((n-2048)>>4)*32 + 16 + (n&15)
__global__ void transpose_w(const float* __restrict__ W, bf16* __restrict__ Wth,
                            bf16* __restrict__ Wtl, int K_, int N_, int perm) {
    __shared__ float tile[32][33];
    int l = blockIdx.z;
    const float* Ws = W + (long)l * K_ * N_;
    long obase = (long)l * K_ * N_;
    int n0 = blockIdx.x * 32, k0 = blockIdx.y * 32;
    int tx = threadIdx.x & 31, ty = threadIdx.x >> 5;   // 32 x 8
    #pragma unroll
    for (int i = 0; i < 32; i += 8)
        tile[ty + i][tx] = Ws[(long)(k0 + ty + i) * N_ + n0 + tx];
    __syncthreads();
    #pragma unroll
    for (int i = 0; i < 32; i += 8) {
        int n = n0 + ty + i;
        int nn = perm ? (((n & 2047) >> 4) * 32 + (n & 15) + (((n >> 11) & 1) << 4)) : n;
        long oidx = obase + (long)nn * K_ + k0 + tx;
        split2(tile[tx][ty + i], Wth + oidx, Wtl + oidx);
    }
}

// ---------------------------------------------------------------- patchify: video -> patches hi/lo [6400][512]
__global__ void patchify(const float* __restrict__ video, bf16* __restrict__ ph,
                         bf16* __restrict__ pl) {
    int idx = blockIdx.x * 256 + threadIdx.x;          // over 6400*512
    int row = idx >> 9, fc = idx & 511;
    if (row >= 6272) { ph[idx] = (bf16)0.f; pl[idx] = (bf16)0.f; return; }
    int bi = row / 3136, t = row % 3136;
    int fi = t / 196, pp = t % 196, hp_i = pp / 14, wp_i = pp % 14;
    int phh = fc >> 5, pw = (fc >> 1) & 15, c = fc & 1;
    long vidx = ((((long)(bi * 16 + fi) * 2 + c) * 224) + hp_i * 16 + phh) * 224 + wp_i * 16 + pw;
    split2(video[vidx], ph + idx, pl + idx);
}

// ---------------------------------------------------------------- x joint-token init
__global__ void xinit(const float* __restrict__ jt, float* __restrict__ x) {
    int idx = blockIdx.x * 256 + threadIdx.x;          // over 2*24*512
    int b = idx / (24 * 512), r = idx % (24 * 512);
    x[(long)b * NTOK * 512 + r] = jt[r];
}

// ---------------------------------------------------------------- axial rotary tables [196][32]
__global__ void sincos_k(float* __restrict__ sinb, float* __restrict__ cosb) {
    int idx = blockIdx.x * 256 + threadIdx.x;
    if (idx >= 196 * 32) return;
    int p = idx >> 5, i = idx & 31;
    int hp_i = p / 14, wp_i = p % 14;
    float coord = (i < 16) ? (-1.f + 2.f * hp_i / 13.f) : (-1.f + 2.f * wp_i / 13.f);
    int si = i & 15;
    float scale = exp2f(si * (float)(2.3219280948873623 / 15.0)); // 2^linspace(0,log2(5),16)
    float ang = coord * scale * 3.14159265358979323846f;
    sinb[idx] = sinf(ang);
    cosb[idx] = cosf(ang);
}

// ---------------------------------------------------------------- LayerNorm fp32 -> bf16 hi/lo (wave per row)
__global__ void ln_kernel(const float* __restrict__ x, const float* __restrict__ w,
                          const float* __restrict__ bb, bf16* __restrict__ oh,
                          bf16* __restrict__ ol, int nreal, int jmap) {
    int row = blockIdx.x * 4 + (threadIdx.x >> 6);
    int lane = threadIdx.x & 63;
    if (row >= nreal) {
        bf8v z;
        #pragma unroll
        for (int i = 0; i < 8; ++i) z[i] = (bf16)0.f;
        *(bf8v*)(oh + (long)row * 512 + lane * 8) = z;
        *(bf8v*)(ol + (long)row * 512 + lane * 8) = z;
        return;
    }
    long src = jmap ? ((long)(row / 24) * NTOK + row % 24) : row;
    const float* xr = x + src * 512 + lane * 8;
    f4v a = *(const f4v*)xr;
    f4v b4 = *(const f4v*)(xr + 4);
    float s = 0.f, sq = 0.f;
    #pragma unroll
    for (int i = 0; i < 4; ++i) { s += a[i] + b4[i]; sq += a[i]*a[i] + b4[i]*b4[i]; }
    #pragma unroll
    for (int off = 32; off; off >>= 1) { s += __shfl_xor(s, off); sq += __shfl_xor(sq, off); }
    float mean = s * (1.f / 512.f);
    float var = sq * (1.f / 512.f) - mean * mean;
    float r = rsqrtf(var + 1e-5f);
    f4v wv0 = *(const f4v*)(w + lane * 8),  wv1 = *(const f4v*)(w + lane * 8 + 4);
    f4v bv0 = *(const f4v*)(bb + lane * 8), bv1 = *(const f4v*)(bb + lane * 8 + 4);
    bf8v vh, vl;
    #pragma unroll
    for (int i = 0; i < 4; ++i) {
        float v0 = (a[i]  - mean) * r * wv0[i] + bv0[i];
        float v1 = (b4[i] - mean) * r * wv1[i] + bv1[i];
        bf16 h0 = (bf16)v0, h1_ = (bf16)v1;
        vh[i] = h0;     vl[i] = (bf16)(v0 - (float)h0);
        vh[i + 4] = h1_; vl[i + 4] = (bf16)(v1 - (float)h1_);
    }
    *(bf8v*)(oh + (long)row * 512 + lane * 8) = vh;
    *(bf8v*)(ol + (long)row * 512 + lane * 8) = vl;
}

// ---------------------------------------------------------------- split-bf16 MFMA GEMM: C = A*B with A=Ah+Al, B=Bh+Bl
// 3-term: Ah*Bh + Ah*Bl + Al*Bh; fp32 accumulate -> ~fp32-accurate.
// LDS slot swizzle (per 16-row slab, slot = r*4 + (q ^ ((r>>2)&3))): the
// stored chunk order is permuted via the per-lane GLOBAL source address
// (global_load_lds dest stays linear), and reads apply the same XOR.
// This spreads fragment ds_read_b128 across all 8 bank-groups (was 8-way
// conflict at byte=row*64+q4*16).
// EPI: 0 = f32 out (+bias)
//      1 = fused gated-GELU (ff1, permuted cols)
//      2 = residual atomicAdd into f32 x[.][512] (supports split-K via blockIdx.z;
//          bias added by kz==0 only)
//      3 = patch row-remap into x
template<int EPI>
__global__ __launch_bounds__(256)
void gemm3_bt(const bf16* __restrict__ Ah, const bf16* __restrict__ Al,
              const bf16* __restrict__ Bh, const bf16* __restrict__ Bl,
              const float* __restrict__ bias, float* __restrict__ outF,
              bf16* __restrict__ oH, bf16* __restrict__ oL,
              int M, int N, int K, int Mstore) {
    __shared__ bf16 LAh[128 * 32];
    __shared__ bf16 LAl[128 * 32];
    __shared__ bf16 LBh[128 * 32];
    __shared__ bf16 LBl[128 * 32];
    int tid = threadIdx.x;
    int wave = tid >> 6, lane = tid & 63;
    long m0 = (long)blockIdx.y * 128;
    long n0 = (long)blockIdx.x * 128;
    int wm = (wave >> 1) * 64, wn = (wave & 1) * 64;
    f4v acc[4][4] = {};
    int r16 = lane & 15, q4 = lane >> 4;
    int srow = lane >> 2;                      // row within 16-row slab
    int cg = (lane & 3) ^ ((lane >> 4) & 3);   // swizzled source chunk

    const bf16* Agh = Ah + m0 * K;
    const bf16* Agl = Al + m0 * K;
    const bf16* Bgh = Bh + n0 * K;
    const bf16* Bgl = Bl + n0 * K;

    int kz = blockIdx.z;
    int kn = K / gridDim.z;
    int kbeg = kz * kn, kend = kbeg + kn;

    for (int kb = kbeg; kb < kend; kb += 32) {
        #pragma unroll
        for (int ss = 0; ss < 2; ++ss) {
            int s = wave * 2 + ss;
            long roff = (long)(s * 16 + srow) * K + kb + cg * 8;
            int ldso = s * 512;   // elements
            __builtin_amdgcn_global_load_lds(
                (const __attribute__((address_space(1))) void*)(Agh + roff),
                (__attribute__((address_space(3))) void*)(LAh + ldso), 16, 0, 0);
            __builtin_amdgcn_global_load_lds(
                (const __attribute__((address_space(1))) void*)(Agl + roff),
                (__attribute__((address_space(3))) void*)(LAl + ldso), 16, 0, 0);
            __builtin_amdgcn_global_load_lds(
                (const __attribute__((address_space(1))) void*)(Bgh + roff),
                (__attribute__((address_space(3))) void*)(LBh + ldso), 16, 0, 0);
            __builtin_amdgcn_global_load_lds(
                (const __attribute__((address_space(1))) void*)(Bgl + roff),
                (__attribute__((address_space(3))) void*)(LBl + ldso), 16, 0, 0);
        }
        __syncthreads();
        int cq = (q4 ^ (r16 >> 2)) * 8;        // swizzled read chunk (elements)
        s8v ah[4], al[4], bh[4], bl[4];
        #pragma unroll
        for (int mb = 0; mb < 4; ++mb) {
            int off = (wm + mb * 16 + r16) * 32 + cq;
            ah[mb] = *(const s8v*)(LAh + off);
            al[mb] = *(const s8v*)(LAl + off);
        }
        #pragma unroll
        for (int nb = 0; nb < 4; ++nb) {
            int off = (wn + nb * 16 + r16) * 32 + cq;
            bh[nb] = *(const s8v*)(LBh + off);
            bl[nb] = *(const s8v*)(LBl + off);
        }
        #pragma unroll
        for (int mb = 0; mb < 4; ++mb)
            #pragma unroll
            for (int nb = 0; nb < 4; ++nb) {
                acc[mb][nb] = __builtin_amdgcn_mfma_f32_16x16x32_bf16(ah[mb], bh[nb], acc[mb][nb], 0, 0, 0);
                acc[mb][nb] = __builtin_amdgcn_mfma_f32_16x16x32_bf16(ah[mb], bl[nb], acc[mb][nb], 0, 0, 0);
                acc[mb][nb] = __builtin_amdgcn_mfma_f32_16x16x32_bf16(al[mb], bh[nb], acc[mb][nb], 0, 0, 0);
            }
        __syncthreads();
    }
    if (EPI == 1) {
        #pragma unroll
        for (int np = 0; np < 2; ++np) {
            int colA = (int)n0 + wn + np * 32 + r16;       // a-subtile col (nb = np*2, offset nb*16)
            int pcol = ((colA >> 5) << 4) + (colA & 15);   // pair idx == orig a-col (0..2047)
            float ba = bias[pcol], bg = bias[pcol + 2048];
            #pragma unroll
            for (int mb = 0; mb < 4; ++mb)
                #pragma unroll
                for (int i = 0; i < 4; ++i) {
                    long row = m0 + wm + mb * 16 + q4 * 4 + i;
                    if (row >= Mstore) continue;
                    float a = acc[mb][np * 2][i] + ba;
                    float g = acc[mb][np * 2 + 1][i] + bg;
                    float gl = 0.5f * g * (1.f + erff(g * 0.70710678118654752f));
                    float v = a * gl;
                    long oidx = row * 2048 + pcol;
                    split2(v, oH + oidx, oL + oidx);
                }
        }
    } else {
        #pragma unroll
        for (int nb = 0; nb < 4; ++nb) {
            int col = (int)n0 + wn + nb * 16 + r16;
            float bv = bias ? bias[col] : 0.f;
            if (EPI == 2 && kz != 0) bv = 0.f;
            #pragma unroll
            for (int mb = 0; mb < 4; ++mb) {
                #pragma unroll
                for (int i = 0; i < 4; ++i) {
                    long row = m0 + wm + mb * 16 + q4 * 4 + i;
                    if (row >= Mstore) continue;
                    float v = acc[mb][nb][i] + bv;
                    if (EPI == 0) outF[row * N + col] = v;
                    else if (EPI == 2) atomicAdd(&outF[row * 512 + col], v);
                    else {  // EPI == 3: rows are b*3136+t -> x row b*3160 + 24 + t
                        long orow = row + 24 * (row / 3136 + 1);
                        outF[orow * 512 + col] = v;
                    }
                }
            }
        }
    }
    (void)M;
}

// ---------------------------------------------------------------- joints attention: S = (jq*scale) @ k^T over all 3160 keys
__global__ void jattn_scores(const float* __restrict__ qkv, float* __restrict__ S) {
    int kt = blockIdx.x, bh = blockIdx.y;
    int b = bh >> 3, h = bh & 7;
    long rowbase = (long)b * NTOK;
    __shared__ float qs[24][64];
    __shared__ float ks[64][65];
    int tid = threadIdx.x;
    for (int idx = tid; idx < 24 * 64; idx += 256) {
        int j = idx >> 6, d = idx & 63;
        qs[j][d] = qkv[(rowbase + j) * 1536 + h * 64 + d] * 0.125f;
    }
    for (int idx = tid; idx < 64 * 64; idx += 256) {
        int j = idx >> 6, d = idx & 63;
        int tok = kt * 64 + j;
        ks[j][d] = (tok < NTOK) ? qkv[(rowbase + tok) * 1536 + 512 + h * 64 + d] : 0.f;
    }
    __syncthreads();
    for (int idx = tid; idx < 24 * 64; idx += 256) {
        int qi = idx >> 6, kk = idx & 63;
        int tok = kt * 64 + kk;
        if (tok >= NTOK) continue;
        float acc = 0.f;
        #pragma unroll 8
        for (int d = 0; d < 64; ++d) acc += qs[qi][d] * ks[kk][d];
        S[((long)bh * 24 + qi) * NTOK + tok] = acc;
    }
}

__global__ void jattn_softmax(float* __restrict__ S) {
    int r = blockIdx.x;                      // 0..383
    float* row = S + (long)r * NTOK;
    int tid = threadIdx.x, wave = tid >> 6, lane = tid & 63;
    __shared__ float wred[4];
    float m = -3e38f;
    for (int i = tid; i < NTOK; i += 256) m = fmaxf(m, row[i]);
    #pragma unroll
    for (int off = 32; off; off >>= 1) m = fmaxf(m, __shfl_xor(m, off));
    if (lane == 0) wred[wave] = m;
    __syncthreads();
    m = fmaxf(fmaxf(wred[0], wred[1]), fmaxf(wred[2], wred[3]));
    __syncthreads();
    float s = 0.f;
    for (int i = tid; i < NTOK; i += 256) { float e = __expf(row[i] - m); row[i] = e; s += e; }
    #pragma unroll
    for (int off = 32; off; off >>= 1) s += __shfl_xor(s, off);
    if (lane == 0) wred[wave] = s;
    __syncthreads();
    s = wred[0] + wred[1] + wred[2] + wred[3];
    float inv = 1.f / s;
    for (int i = tid; i < NTOK; i += 256) row[i] *= inv;
}

// ---------------------------------------------------------------- joints PV: grid (8 key-chunks, 16 bh)
__global__ __launch_bounds__(256)
void jattn_pv(const float* __restrict__ qkv, const float* __restrict__ S,
              float* __restrict__ jo4) {
    int kc = blockIdx.x, bh = blockIdx.y;
    int b = bh >> 3, h = bh & 7;
    long rowbase = (long)b * NTOK;
    int kbase = kc * 395;                    // 3160 = 8 * 395
    __shared__ __align__(16) float LsT[395][28];
    __shared__ float ob[4][24][64];
    int tid = threadIdx.x, w = tid >> 6, lane = tid & 63;
    for (int q = 0; q < 24; ++q) {
        const float* Pr = S + ((long)bh * 24 + q) * NTOK + kbase;
        for (int jj = tid; jj < 395; jj += 256) LsT[jj][q] = Pr[jj];
    }
    __syncthreads();
    float o[24] = {};
    for (int jj = w; jj < 395; jj += 4) {
        float v = qkv[(rowbase + kbase + jj) * 1536 + 1024 + h * 64 + lane];
        #pragma unroll
        for (int q = 0; q < 24; q += 4) {
            f4v p = *(const f4v*)&LsT[jj][q];
            o[q]     += p[0] * v;
            o[q + 1] += p[1] * v;
            o[q + 2] += p[2] * v;
            o[q + 3] += p[3] * v;
        }
    }
    #pragma unroll
    for (int q = 0; q < 24; ++q) ob[w][q][lane] = o[q];
    __syncthreads();
    for (int idx = tid; idx < 24 * 64; idx += 256) {
        int q = idx >> 6, d = idx & 63;
        jo4[(((long)kc * 16 + bh) * 24 + q) * 64 + d] =
            ob[0][q][d] + ob[1][q][d] + ob[2][q][d] + ob[3][q][d];
    }
}

__global__ void jattn_fin(const float* __restrict__ jo4, bf16* __restrict__ aoh,
                          bf16* __restrict__ aol) {
    int idx = blockIdx.x * 256 + threadIdx.x;  // over 16*24*64 = 24576
    if (idx >= 16 * 24 * 64) return;
    int bh = idx / 1536, r = idx % 1536;       // per-bh span = 24*64 = 1536
    int b = bh >> 3, h = bh & 7;
    int q = r >> 6, d = r & 63;
    float s = 0.f;
    #pragma unroll
    for (int kc = 0; kc < 8; ++kc)
        s += jo4[(((long)kc * 16 + bh) * 24 + q) * 64 + d];
    long oidx = ((long)b * NTOK + q) * 512 + h * 64 + d;
    split2(s, aoh + oidx, aol + oidx);
}

// ---------------------------------------------------------------- frame attention, MFMA version
__global__ __launch_bounds__(256, 1)
void frame_attn(const float* __restrict__ qkv, const float* __restrict__ sinb,
                const float* __restrict__ cosb, bf16* __restrict__ aoh,
                bf16* __restrict__ aol) {
    int fr = blockIdx.x, bh = blockIdx.y;
    int b = bh >> 3, h = bh & 7;
    long rowbase = (long)b * NTOK;
    int t0 = 24 + fr * 196;

    __shared__ __align__(16) bf16 Ks[224 * 64];     // 28672 B
    __shared__ __align__(16) bf16 Qh[224 * 64];     // 28672
    __shared__ __align__(16) bf16 Ql[224 * 64];     // 28672
    __shared__ __align__(16) bf16 Vh[64 * 224];     // 28672
    __shared__ __align__(16) bf16 Vl[64 * 224];     // 28672
    __shared__ __align__(16) bf16 Ph[4 * 16 * 64];  // 8192
    __shared__ __align__(16) bf16 Pl[4 * 16 * 64];  // 8192  => total 159744 B

    int tid = threadIdx.x;
    for (int idx = tid; idx < 224 * 16; idx += 256) {
        int j = idx >> 4, d4 = idx & 15;
        int tok = (j < 24) ? j : (t0 + j - 24);
        bf4v kb;
        if (j < 220) {
            f4v kv = *(const f4v*)(qkv + (rowbase + tok) * 1536 + 512 + h * 64 + d4 * 4);
            if (j >= 24) {
                int pos = j - 24;
                float sn0 = sinb[pos * 32 + d4 * 2],     cs0 = cosb[pos * 32 + d4 * 2];
                float sn1 = sinb[pos * 32 + d4 * 2 + 1], cs1 = cosb[pos * 32 + d4 * 2 + 1];
                kb[0] = (bf16)(kv[0] * cs0 - kv[1] * sn0);
                kb[1] = (bf16)(kv[1] * cs0 + kv[0] * sn0);
                kb[2] = (bf16)(kv[2] * cs1 - kv[3] * sn1);
                kb[3] = (bf16)(kv[3] * cs1 + kv[2] * sn1);
            } else {
                kb[0] = (bf16)kv[0]; kb[1] = (bf16)kv[1];
                kb[2] = (bf16)kv[2]; kb[3] = (bf16)kv[3];
            }
        } else {
            kb[0] = kb[1] = kb[2] = kb[3] = (bf16)0.f;
        }
        *(bf4v*)((char*)Ks + ((j * 128 + d4 * 8) ^ ((j & 7) << 4))) = kb;
        bf4v qhv, qlv;
        if (j < 196) {
            f4v qv = *(const f4v*)(qkv + (rowbase + t0 + j) * 1536 + h * 64 + d4 * 4);
            float sn0 = sinb[j * 32 + d4 * 2],     cs0 = cosb[j * 32 + d4 * 2];
            float sn1 = sinb[j * 32 + d4 * 2 + 1], cs1 = cosb[j * 32 + d4 * 2 + 1];
            float r0 = (qv[0] * cs0 - qv[1] * sn0) * 0.125f;
            float r1 = (qv[1] * cs0 + qv[0] * sn0) * 0.125f;
            float r2 = (qv[2] * cs1 - qv[3] * sn1) * 0.125f;
            float r3 = (qv[3] * cs1 + qv[2] * sn1) * 0.125f;
            bf16 h0 = (bf16)r0; qhv[0] = h0; qlv[0] = (bf16)(r0 - (float)h0);
            bf16 h1 = (bf16)r1; qhv[1] = h1; qlv[1] = (bf16)(r1 - (float)h1);
            bf16 h2 = (bf16)r2; qhv[2] = h2; qlv[2] = (bf16)(r2 - (float)h2);
            bf16 h3 = (bf16)r3; qhv[3] = h3; qlv[3] = (bf16)(r3 - (float)h3);
        } else {
            qhv[0] = qhv[1] = qhv[2] = qhv[3] = (bf16)0.f;
            qlv[0] = qlv[1] = qlv[2] = qlv[3] = (bf16)0.f;
        }
        int qoff = (j * 128 + d4 * 8) ^ ((j & 7) << 4);
        *(bf4v*)((char*)Qh + qoff) = qhv;
        *(bf4v*)((char*)Ql + qoff) = qlv;
        f4v vv = {0.f, 0.f, 0.f, 0.f};
        if (j < 220)
            vv = *(const f4v*)(qkv + (rowbase + tok) * 1536 + 1024 + h * 64 + d4 * 4);
        #pragma unroll
        for (int k = 0; k < 4; ++k) {
            int d = d4 * 4 + k;
            int vo = (d * 448 + j * 2) ^ ((d & 3) << 4);
            bf16 hv = (bf16)vv[k];
            *(bf16*)((char*)Vh + vo) = hv;
            *(bf16*)((char*)Vl + vo) = (bf16)(vv[k] - (float)hv);
        }
    }
    __syncthreads();

    int w = tid >> 6, lane = tid & 63;
    int r16 = lane & 15, q4 = lane >> 4;
    char* PhB = (char*)Ph + w * 2048;
    char* PlB = (char*)Pl + w * 2048;
    int nt = (w == 3) ? 2 : 4;

    for (int jt = 0; jt < nt; ++jt) {
        int qt = w * 4 + jt;
        int qrow = qt * 16 + r16;
        int qsw = (qrow & 7) << 4;
        s8v ah0 = *(const s8v*)((char*)Qh + ((qrow * 128 + q4 * 16) ^ qsw));
        s8v ah1 = *(const s8v*)((char*)Qh + ((qrow * 128 + 64 + q4 * 16) ^ qsw));
        s8v al0 = *(const s8v*)((char*)Ql + ((qrow * 128 + q4 * 16) ^ qsw));
        s8v al1 = *(const s8v*)((char*)Ql + ((qrow * 128 + 64 + q4 * 16) ^ qsw));
        f4v s[14];
        #pragma unroll
        for (int kt = 0; kt < 14; ++kt) {
            int krow = kt * 16 + r16;
            int ksw = (krow & 7) << 4;
            s8v b0 = *(const s8v*)((char*)Ks + ((krow * 128 + q4 * 16) ^ ksw));
            s8v b1 = *(const s8v*)((char*)Ks + ((krow * 128 + 64 + q4 * 16) ^ ksw));
            f4v a = {0.f, 0.f, 0.f, 0.f};
            a = __builtin_amdgcn_mfma_f32_16x16x32_bf16(ah0, b0, a, 0, 0, 0);
            a = __builtin_amdgcn_mfma_f32_16x16x32_bf16(ah1, b1, a, 0, 0, 0);
            a = __builtin_amdgcn_mfma_f32_16x16x32_bf16(al0, b0, a, 0, 0, 0);
            a = __builtin_amdgcn_mfma_f32_16x16x32_bf16(al1, b1, a, 0, 0, 0);
            s[kt] = a;
        }
        if (r16 >= 12) { s[13][0] = -3e38f; s[13][1] = -3e38f; s[13][2] = -3e38f; s[13][3] = -3e38f; }
        f4v m = s[0];
        #pragma unroll
        for (int kt = 1; kt < 14; ++kt)
            #pragma unroll
            for (int i = 0; i < 4; ++i) m[i] = fmaxf(m[i], s[kt][i]);
        #pragma unroll
        for (int off = 1; off <= 8; off <<= 1)
            #pragma unroll
            for (int i = 0; i < 4; ++i) m[i] = fmaxf(m[i], __shfl_xor(m[i], off));
        f4v sum = {0.f, 0.f, 0.f, 0.f};
        #pragma unroll
        for (int kt = 0; kt < 14; ++kt)
            #pragma unroll
            for (int i = 0; i < 4; ++i) { s[kt][i] = __expf(s[kt][i] - m[i]); sum[i] += s[kt][i]; }
        #pragma unroll
        for (int off = 1; off <= 8; off <<= 1)
            #pragma unroll
            for (int i = 0; i < 4; ++i) sum[i] += __shfl_xor(sum[i], off);
        f4v inv;
        #pragma unroll
        for (int i = 0; i < 4; ++i) inv[i] = 1.f / sum[i];
        #pragma unroll
        for (int kt = 0; kt < 14; ++kt)
            #pragma unroll
            for (int i = 0; i < 4; ++i) s[kt][i] *= inv[i];

        f4v o[4] = {{0.f,0.f,0.f,0.f},{0.f,0.f,0.f,0.f},{0.f,0.f,0.f,0.f},{0.f,0.f,0.f,0.f}};
        #pragma unroll
        for (int ks = 0; ks < 7; ++ks) {
            #pragma unroll
            for (int half = 0; half < 2; ++half) {
                int kt = ks * 2 + half;
                #pragma unroll
                for (int i = 0; i < 4; ++i) {
                    int prow = q4 * 4 + i;
                    int pbyte = (prow * 128 + (half * 16 + r16) * 2) ^ ((prow & 7) << 4);
                    float p = s[kt][i];
                    bf16 hb = (bf16)p;
                    *(bf16*)(PhB + pbyte) = hb;
                    *(bf16*)(PlB + pbyte) = (bf16)(p - (float)hb);
                }
            }
            int abyte = (r16 * 128 + q4 * 16) ^ ((r16 & 7) << 4);
            s8v pah = *(const s8v*)(PhB + abyte);
            s8v pal = *(const s8v*)(PlB + abyte);
            #pragma unroll
            for (int dt = 0; dt < 4; ++dt) {
                int vrow = dt * 16 + r16;
                int vbyte = (vrow * 448 + ks * 64 + q4 * 16) ^ ((vrow & 3) << 4);
                s8v bvh = *(const s8v*)((char*)Vh + vbyte);
                s8v bvl = *(const s8v*)((char*)Vl + vbyte);
                o[dt] = __builtin_amdgcn_mfma_f32_16x16x32_bf16(pah, bvh, o[dt], 0, 0, 0);
                o[dt] = __builtin_amdgcn_mfma_f32_16x16x32_bf16(pal, bvh, o[dt], 0, 0, 0);
                o[dt] = __builtin_amdgcn_mfma_f32_16x16x32_bf16(pah, bvl, o[dt], 0, 0, 0);
            }
        }
        #pragma unroll
        for (int dt = 0; dt < 4; ++dt)
            #pragma unroll
            for (int i = 0; i < 4; ++i) {
                int query = qt * 16 + q4 * 4 + i;
                if (query < 196) {
                    long oidx = (rowbase + t0 + query) * 512 + h * 64 + dt * 16 + r16;
                    split2(o[dt][i], aoh + oidx, aol + oidx);
                }
            }
    }
}

// ----------------------------------------------------------------
extern "C" void kernel_launch(void* const* d_in, const int* in_sizes, int n_in,
                              void* d_out, int out_size, void* d_ws, size_t ws_size,
                              hipStream_t stream) {
    const float* video        = (const float*)d_in[0];
    const float* patch_w      = (const float*)d_in[1];
    const float* patch_b      = (const float*)d_in[2];
    const float* joints_token = (const float*)d_in[3];
    const float* ln_attn_w    = (const float*)d_in[4];
    const float* ln_attn_b    = (const float*)d_in[5];
    const float* qkv_w        = (const float*)d_in[6];
    const float* attn_out_w   = (const float*)d_in[7];
    const float* attn_out_b   = (const float*)d_in[8];
    const float* ln_ff_w      = (const float*)d_in[9];
    const float* ln_ff_b      = (const float*)d_in[10];
    const float* ff1_w        = (const float*)d_in[11];
    const float* ff1_b        = (const float*)d_in[12];
    const float* ff2_w        = (const float*)d_in[13];
    const float* ff2_b        = (const float*)d_in[14];
    const float* ln_out_w     = (const float*)d_in[15];
    const float* ln_out_b     = (const float*)d_in[16];
    const float* out_w        = (const float*)d_in[17];
    const float* out_b        = (const float*)d_in[18];
    float* out = (float*)d_out;

    char* ws = (char*)d_ws;
    size_t off = 0;
    auto alloc = [&](size_t bytes) { void* p = ws + off; off += (bytes + 255) & ~(size_t)255; return p; };

    // ---- common buffers
    float* x    = (float*)alloc((long)MPAD * 512 * 4);
    bf16* xnh   = (bf16*)alloc((long)MPAD * 512 * 2);
    bf16* xnl   = (bf16*)alloc((long)MPAD * 512 * 2);
    bf16* hgh   = (bf16*)alloc((long)MPAD * 2048 * 2);
    bf16* hgl   = (bf16*)alloc((long)MPAD * 2048 * 2);
    float* sinb = (float*)alloc(196l * 32 * 4);
    float* cosb = (float*)alloc(196l * 32 * 4);
    bf16* pwh   = (bf16*)alloc(512l * 512 * 2);
    bf16* pwl   = (bf16*)alloc(512l * 512 * 2);
    bf16* owh   = (bf16*)alloc(384l * 512 * 2);
    bf16* owl   = (bf16*)alloc(384l * 512 * 2);
    // union region (104.9 MB): {qkvb f32 | S | aoh | aol | jo4} vs {patches hi/lo} vs {jn hi/lo}
    char* U     = (char*)alloc(104857600);
    float* qkvb = (float*)U;                           // [6400][1536] f32 (0 .. 39,321,600)
    float* S    = (float*)(U + 39321600);              // [16][24][3160] f32 (ends 44,175,360)
    bf16* aoh   = (bf16*)(U + 44175360);               // [6400][512] (ends 50,728,960)
    bf16* aol   = (bf16*)(U + 50728960);               // [6400][512] (ends 57,282,560)
    float* jo4  = (float*)(U + 57282560);              // [8][16][24][64] f32 (ends 58,068,992)
    bf16* ph    = (bf16*)U;                            // patches (setup only)
    bf16* pl    = (bf16*)(U + 6553600);
    bf16* jnh   = (bf16*)U;                            // [128][512] (final only)
    bf16* jnl   = (bf16*)(U + 131072);

    // ---- weight storage: persistent if workspace allows, else per-layer staging
    size_t base_off = off;
    bool persist = ws_size >= base_off + 202000000;    // need ~201.3 MB more
    bf16 *qkvWh, *qkvWl, *aoWh, *aoWl, *f1Wh, *f1Wl, *f2Wh, *f2Wl;
    long sz_qkv = 1536l * 512, sz_ao = 512l * 512, sz_f1 = 4096l * 512, sz_f2 = 512l * 2048;
    if (persist) {
        qkvWh = (bf16*)alloc(12 * sz_qkv * 2); qkvWl = (bf16*)alloc(12 * sz_qkv * 2);
        aoWh  = (bf16*)alloc(12 * sz_ao * 2);  aoWl  = (bf16*)alloc(12 * sz_ao * 2);
        f1Wh  = (bf16*)alloc(12 * sz_f1 * 2);  f1Wl  = (bf16*)alloc(12 * sz_f1 * 2);
        f2Wh  = (bf16*)alloc(12 * sz_f2 * 2);  f2Wl  = (bf16*)alloc(12 * sz_f2 * 2);
    } else {
        qkvWh = (bf16*)alloc(sz_qkv * 2); qkvWl = (bf16*)alloc(sz_qkv * 2);
        aoWh  = (bf16*)alloc(sz_ao * 2);  aoWl  = (bf16*)alloc(sz_ao * 2);
        f1Wh  = (bf16*)alloc(sz_f1 * 2);  f1Wl  = (bf16*)alloc(sz_f1 * 2);
        f2Wh  = (bf16*)alloc(sz_f2 * 2);  f2Wl  = (bf16*)alloc(sz_f2 * 2);
    }

    // ---- setup
    if (persist) {
        transpose_w<<<dim3(48, 16, 12), 256, 0, stream>>>(qkv_w, qkvWh, qkvWl, 512, 1536, 0);
        transpose_w<<<dim3(16, 16, 12), 256, 0, stream>>>(attn_out_w, aoWh, aoWl, 512, 512, 0);
        transpose_w<<<dim3(128, 16, 12), 256, 0, stream>>>(ff1_w, f1Wh, f1Wl, 512, 4096, 1);
        transpose_w<<<dim3(16, 64, 12), 256, 0, stream>>>(ff2_w, f2Wh, f2Wl, 2048, 512, 0);
    }
    transpose_w<<<dim3(16, 16, 1), 256, 0, stream>>>(patch_w, pwh, pwl, 512, 512, 0);
    transpose_w<<<dim3(12, 16, 1), 256, 0, stream>>>(out_w, owh, owl, 512, 384, 0);
    patchify<<<12800, 256, 0, stream>>>(video, ph, pl);
    xinit<<<96, 256, 0, stream>>>(joints_token, x);
    sincos_k<<<25, 256, 0, stream>>>(sinb, cosb);
    gemm3_bt<3><<<dim3(4, 49), 256, 0, stream>>>(ph, pl, pwh, pwl, patch_b, x, nullptr, nullptr, 6272, 512, 512, 6272);

    for (int l = 0; l < 12; ++l) {
        long lq = persist ? l * sz_qkv : 0, la = persist ? l * sz_ao : 0;
        long l1 = persist ? l * sz_f1 : 0, l2 = persist ? l * sz_f2 : 0;
        if (!persist) {
            transpose_w<<<dim3(48, 16, 1), 256, 0, stream>>>(qkv_w + l * sz_qkv, qkvWh, qkvWl, 512, 1536, 0);
            transpose_w<<<dim3(16, 16, 1), 256, 0, stream>>>(attn_out_w + l * sz_ao, aoWh, aoWl, 512, 512, 0);
            transpose_w<<<dim3(128, 16, 1), 256, 0, stream>>>(ff1_w + l * sz_f1, f1Wh, f1Wl, 512, 4096, 1);
            transpose_w<<<dim3(16, 64, 1), 256, 0, stream>>>(ff2_w + l * sz_f2, f2Wh, f2Wl, 2048, 512, 0);
        }
        ln_kernel<<<1600, 256, 0, stream>>>(x, ln_attn_w + l * 512, ln_attn_b + l * 512, xnh, xnl, MROWS, 0);
        gemm3_bt<0><<<dim3(12, 50), 256, 0, stream>>>(xnh, xnl, qkvWh + lq, qkvWl + lq, nullptr, qkvb, nullptr, nullptr, MPAD, 1536, 512, MPAD);
        jattn_scores<<<dim3(50, 16), 256, 0, stream>>>(qkvb, S);
        jattn_softmax<<<384, 256, 0, stream>>>(S);
        jattn_pv<<<dim3(8, 16), 256, 0, stream>>>(qkvb, S, jo4);
        jattn_fin<<<96, 256, 0, stream>>>(jo4, aoh, aol);
        frame_attn<<<dim3(16, 16), 256, 0, stream>>>(qkvb, sinb, cosb, aoh, aol);
        gemm3_bt<2><<<dim3(4, 50, 2), 256, 0, stream>>>(aoh, aol, aoWh + la, aoWl + la, attn_out_b + l * 512, x, nullptr, nullptr, MPAD, 512, 512, MROWS);
        ln_kernel<<<1600, 256, 0, stream>>>(x, ln_ff_w + l * 512, ln_ff_b + l * 512, xnh, xnl, MROWS, 0);
        gemm3_bt<1><<<dim3(32, 50), 256, 0, stream>>>(xnh, xnl, f1Wh + l1, f1Wl + l1, ff1_b + l * 4096, nullptr, hgh, hgl, MPAD, 4096, 512, MPAD);
        gemm3_bt<2><<<dim3(4, 50, 2), 256, 0, stream>>>(hgh, hgl, f2Wh + l2, f2Wl + l2, ff2_b + l * 512, x, nullptr, nullptr, MPAD, 512, 2048, MROWS);
    }
    ln_kernel<<<32, 256, 0, stream>>>(x, ln_out_w, ln_out_b, jnh, jnl, 48, 1);
    gemm3_bt<0><<<dim3(3, 1), 256, 0, stream>>>(jnh, jnl, owh, owl, out_b, out, nullptr, nullptr, 128, 384, 512, 48);
    (void)in_sizes; (void)n_in; (void)out_size;
}